// Round 1
// baseline (1055.524 us; speedup 1.0000x reference)
//
#include <hip/hip_runtime.h>
#include <math.h>

// S5 SSM forward, fp32 correctness-first implementation.
// BSZ=4, L=4096, H=1024, P=512.
//
// ws layout (float2 elements):
//   [0, P*H)              Bbar (complex, row-major [p][h])
//   [P*H, P*H+512)        Lambda_bar (complex, per p)
//   [P*H+1024, +B*P*L)    Bu -> xs (in-place scan), [b][p][l] complex

constexpr int kB = 4;
constexpr int kL = 4096;
constexpr int kH = 1024;
constexpr int kP = 512;

constexpr size_t BBAR_OFF = 0;
constexpr size_t LBAR_OFF = (size_t)kP * kH;       // 524288
constexpr size_t BU_OFF   = LBAR_OFF + 1024;       // 525312 (16B aligned)

// ---------------------------------------------------------------- precompute
__global__ __launch_bounds__(256) void k_precompute(
    const float* __restrict__ Lre, const float* __restrict__ Lim,
    const float* __restrict__ B,   const float* __restrict__ log_step,
    float2* __restrict__ ws) {
  int p = blockIdx.x;
  float lr = Lre[p], li = Lim[p];
  float step = expf(log_step[p]);
  // Lambda_bar = exp((lr + i*li) * step)
  float er = expf(lr * step);
  float sb, cb;
  sincosf(li * step, &sb, &cb);
  float lbr = er * cb, lbi = er * sb;
  // B_scale = (Lambda_bar - 1) / Lambda   (complex divide)
  float nr = lbr - 1.0f, ni = lbi;
  float den = lr * lr + li * li;
  float inv = 1.0f / den;
  float sr = (nr * lr + ni * li) * inv;
  float si = (ni * lr - nr * li) * inv;

  if (threadIdx.x == 0) ws[LBAR_OFF + p] = make_float2(lbr, lbi);

  float2* Bbar = ws + BBAR_OFF;
  const float* Brow = B + (size_t)p * kH * 2;
  for (int h = threadIdx.x; h < kH; h += 256) {
    float br = Brow[2 * h + 0];
    float bi = Brow[2 * h + 1];
    Bbar[(size_t)p * kH + h] = make_float2(sr * br - si * bi, sr * bi + si * br);
  }
}

// ---------------------------------------------------------------- GEMM1
// Bu[b][p][l] = sum_h Bbar[p][h] * u[b][h][l]   (complex A, real B)
// M=P=512, N=L=4096, K=H=1024. Tile 64x64x16, micro 4x4.
__global__ __launch_bounds__(256) void k_gemm1(
    const float2* __restrict__ ws_bbar, const float* __restrict__ u,
    float2* __restrict__ Bu) {
  __shared__ float2 As[16][64];   // [kk][m]
  __shared__ float  Bs[16][64];   // [kk][n]

  int b  = blockIdx.z;
  int m0 = blockIdx.y * 64;   // p
  int n0 = blockIdx.x * 64;   // l
  int tid = threadIdx.x;
  int tn = tid & 15, tm = tid >> 4;

  const float* uB = u + (size_t)b * kH * kL;

  float2 acc[4][4];
#pragma unroll
  for (int i = 0; i < 4; i++)
#pragma unroll
    for (int j = 0; j < 4; j++) acc[i][j] = make_float2(0.f, 0.f);

  int ar = tid >> 2;            // 0..63 row for A load
  int ac = (tid & 3) * 4;       // 0,4,8,12
  int bk = tid >> 4;            // 0..15 row for B load
  int bc = (tid & 15) * 4;      // 0..60

  for (int k0 = 0; k0 < kH; k0 += 16) {
    // A tile: Bbar[m0+ar][k0+ac .. +3] -> As[ac..][ar] (transposed store)
    {
      const float4* src = (const float4*)(ws_bbar + (size_t)(m0 + ar) * kH + k0 + ac);
      float4 v01 = src[0];
      float4 v23 = src[1];
      As[ac + 0][ar] = make_float2(v01.x, v01.y);
      As[ac + 1][ar] = make_float2(v01.z, v01.w);
      As[ac + 2][ar] = make_float2(v23.x, v23.y);
      As[ac + 3][ar] = make_float2(v23.z, v23.w);
    }
    // B tile: u[k0+bk][n0+bc .. +3]
    {
      float4 v = *(const float4*)(uB + (size_t)(k0 + bk) * kL + n0 + bc);
      *(float4*)&Bs[bk][bc] = v;
    }
    __syncthreads();

#pragma unroll
    for (int kk = 0; kk < 16; ++kk) {
      const float4* arow = (const float4*)&As[kk][0];
      float4 a01 = arow[tm * 2 + 0];
      float4 a23 = arow[tm * 2 + 1];
      float2 a[4] = {make_float2(a01.x, a01.y), make_float2(a01.z, a01.w),
                     make_float2(a23.x, a23.y), make_float2(a23.z, a23.w)};
      float4 bv = ((const float4*)&Bs[kk][0])[tn];
      float bb[4] = {bv.x, bv.y, bv.z, bv.w};
#pragma unroll
      for (int mi = 0; mi < 4; mi++)
#pragma unroll
        for (int ni = 0; ni < 4; ni++) {
          acc[mi][ni].x = fmaf(a[mi].x, bb[ni], acc[mi][ni].x);
          acc[mi][ni].y = fmaf(a[mi].y, bb[ni], acc[mi][ni].y);
        }
    }
    __syncthreads();
  }

  float2* BuB = Bu + (size_t)b * kP * kL;
#pragma unroll
  for (int mi = 0; mi < 4; mi++) {
    int row = m0 + tm * 4 + mi;
    float2* dst = BuB + (size_t)row * kL + n0 + tn * 4;
    float4 s0 = make_float4(acc[mi][0].x, acc[mi][0].y, acc[mi][1].x, acc[mi][1].y);
    float4 s1 = make_float4(acc[mi][2].x, acc[mi][2].y, acc[mi][3].x, acc[mi][3].y);
    ((float4*)dst)[0] = s0;
    ((float4*)dst)[1] = s1;
  }
}

// ---------------------------------------------------------------- scan
// In-place along l: x[l] = lam * x[l-1] + Bu[l], complex. One block per (b,p).
__global__ __launch_bounds__(256) void k_scan(float2* __restrict__ Bu,
                                              const float2* __restrict__ Lbar) {
  int p = blockIdx.x & (kP - 1);
  int b = blockIdx.x >> 9;
  int tid = threadIdx.x;
  int lane = tid & 63;
  int w = tid >> 6;

  float2 lam = Lbar[p];
  float2* seq = Bu + ((size_t)b * kP + p) * kL;

  float2 v[16];
  {
    const float4* src = (const float4*)(seq + tid * 16);
#pragma unroll
    for (int i = 0; i < 8; i++) {
      float4 t = src[i];
      v[2 * i + 0] = make_float2(t.x, t.y);
      v[2 * i + 1] = make_float2(t.z, t.w);
    }
  }

  // local scan from zero
  float xr = 0.f, xi = 0.f;
#pragma unroll
  for (int i = 0; i < 16; i++) {
    float nr2 = fmaf(lam.x, xr, fmaf(-lam.y, xi, v[i].x));
    float ni2 = fmaf(lam.x, xi, fmaf(lam.y, xr, v[i].y));
    xr = nr2; xi = ni2;
  }

  // lam^16 by repeated squaring
  float Ar = lam.x, Ai = lam.y;
#pragma unroll
  for (int s = 0; s < 4; s++) {
    float t_r = Ar * Ar - Ai * Ai;
    float t_i = 2.f * Ar * Ai;
    Ar = t_r; Ai = t_i;
  }
  float br = xr, bi = xi;

  // wave-level inclusive scan of (A, b) pairs
  for (int off = 1; off < 64; off <<= 1) {
    float pAr = __shfl_up(Ar, off);
    float pAi = __shfl_up(Ai, off);
    float pbr = __shfl_up(br, off);
    float pbi = __shfl_up(bi, off);
    if (lane >= off) {
      float nAr = Ar * pAr - Ai * pAi;
      float nAi = Ar * pAi + Ai * pAr;
      float nbr = Ar * pbr - Ai * pbi + br;
      float nbi = Ar * pbi + Ai * pbr + bi;
      Ar = nAr; Ai = nAi; br = nbr; bi = nbi;
    }
  }

  __shared__ float4 wtot[4];
  if (lane == 63) wtot[w] = make_float4(Ar, Ai, br, bi);
  __syncthreads();

  // exclusive within wave
  float eAr = __shfl_up(Ar, 1);
  float eAi = __shfl_up(Ai, 1);
  float ebr = __shfl_up(br, 1);
  float ebi = __shfl_up(bi, 1);
  if (lane == 0) { eAr = 1.f; eAi = 0.f; ebr = 0.f; ebi = 0.f; }

  // prefix over earlier waves
  float pAr = 1.f, pAi = 0.f, pbr = 0.f, pbi = 0.f;
  for (int j = 0; j < w; j++) {
    float4 t = wtot[j];
    float nAr = t.x * pAr - t.y * pAi;
    float nAi = t.x * pAi + t.y * pAr;
    float nbr = t.x * pbr - t.y * pbi + t.z;
    float nbi = t.x * pbi + t.y * pbr + t.w;
    pAr = nAr; pAi = nAi; pbr = nbr; pbi = nbi;
  }

  // initial state entering this thread's chunk = (e ∘ p).b
  float initr = eAr * pbr - eAi * pbi + ebr;
  float initi = eAr * pbi + eAi * pbr + ebi;

  // rescan with seed, write back in place
  xr = initr; xi = initi;
  float4* dst = (float4*)(seq + tid * 16);
#pragma unroll
  for (int i = 0; i < 8; i++) {
    float nr0 = fmaf(lam.x, xr, fmaf(-lam.y, xi, v[2 * i].x));
    float ni0 = fmaf(lam.x, xi, fmaf(lam.y, xr, v[2 * i].y));
    float nr1 = fmaf(lam.x, nr0, fmaf(-lam.y, ni0, v[2 * i + 1].x));
    float ni1 = fmaf(lam.x, ni0, fmaf(lam.y, nr0, v[2 * i + 1].y));
    dst[i] = make_float4(nr0, ni0, nr1, ni1);
    xr = nr1; xi = ni1;
  }
}

// ---------------------------------------------------------------- GEMM2
// out[b][h][l] = gelu( 2*sum_p (Cr[h][p]*Xr[b][p][l] - Ci[h][p]*Xi[b][p][l])
//                      + D[h]*u[b][h][l] )
// M=H=1024, N=L=4096, K=P=512. Tile 64x64x16, micro 4x4.
__global__ __launch_bounds__(256) void k_gemm2(
    const float2* __restrict__ C, const float2* __restrict__ X,
    const float* __restrict__ u, const float* __restrict__ D,
    float* __restrict__ out) {
  __shared__ float2 As[16][64];   // C tile [kk][m]
  __shared__ float2 Bs[16][64];   // X tile [kk][n]

  int b  = blockIdx.z;
  int m0 = blockIdx.y * 64;   // h
  int n0 = blockIdx.x * 64;   // l
  int tid = threadIdx.x;
  int tn = tid & 15, tm = tid >> 4;

  const float2* Xb = X + (size_t)b * kP * kL;

  float acc[4][4];
#pragma unroll
  for (int i = 0; i < 4; i++)
#pragma unroll
    for (int j = 0; j < 4; j++) acc[i][j] = 0.f;

  int ar = tid >> 2;
  int ac = (tid & 3) * 4;
  int bk = tid >> 4;
  int bc = (tid & 15) * 4;

  for (int k0 = 0; k0 < kP; k0 += 16) {
    {
      const float4* src = (const float4*)(C + (size_t)(m0 + ar) * kP + k0 + ac);
      float4 v01 = src[0];
      float4 v23 = src[1];
      As[ac + 0][ar] = make_float2(v01.x, v01.y);
      As[ac + 1][ar] = make_float2(v01.z, v01.w);
      As[ac + 2][ar] = make_float2(v23.x, v23.y);
      As[ac + 3][ar] = make_float2(v23.z, v23.w);
    }
    {
      const float4* src = (const float4*)(Xb + (size_t)(k0 + bk) * kL + n0 + bc);
      float4 v0 = src[0];
      float4 v1 = src[1];
      ((float4*)&Bs[bk][bc])[0] = v0;
      ((float4*)&Bs[bk][bc])[1] = v1;
    }
    __syncthreads();

#pragma unroll
    for (int kk = 0; kk < 16; ++kk) {
      const float4* arow = (const float4*)&As[kk][0];
      float4 a01 = arow[tm * 2 + 0];
      float4 a23 = arow[tm * 2 + 1];
      float2 a[4] = {make_float2(a01.x, a01.y), make_float2(a01.z, a01.w),
                     make_float2(a23.x, a23.y), make_float2(a23.z, a23.w)};
      const float4* brow = (const float4*)&Bs[kk][0];
      float4 b01 = brow[tn * 2 + 0];
      float4 b23 = brow[tn * 2 + 1];
      float2 bb[4] = {make_float2(b01.x, b01.y), make_float2(b01.z, b01.w),
                      make_float2(b23.x, b23.y), make_float2(b23.z, b23.w)};
#pragma unroll
      for (int mi = 0; mi < 4; mi++)
#pragma unroll
        for (int ni = 0; ni < 4; ni++) {
          acc[mi][ni] = fmaf(a[mi].x, bb[ni].x, acc[mi][ni]);
          acc[mi][ni] = fmaf(-a[mi].y, bb[ni].y, acc[mi][ni]);
        }
    }
    __syncthreads();
  }

  // epilogue: 2*acc + D*u, exact gelu, store in (b,h,l) layout
#pragma unroll
  for (int mi = 0; mi < 4; mi++) {
    int h = m0 + tm * 4 + mi;
    float d = D[h];
    const float* urow = u + ((size_t)b * kH + h) * kL + n0 + tn * 4;
    float4 uv = *(const float4*)urow;
    float uu[4] = {uv.x, uv.y, uv.z, uv.w};
    float res[4];
#pragma unroll
    for (int ni = 0; ni < 4; ni++) {
      float y = 2.f * acc[mi][ni] + d * uu[ni];
      res[ni] = 0.5f * y * (1.f + erff(y * 0.70710678118654752f));
    }
    float* orow = out + ((size_t)b * kH + h) * kL + n0 + tn * 4;
    *(float4*)orow = make_float4(res[0], res[1], res[2], res[3]);
  }
}

// ---------------------------------------------------------------- launch
extern "C" void kernel_launch(void* const* d_in, const int* in_sizes, int n_in,
                              void* d_out, int out_size, void* d_ws, size_t ws_size,
                              hipStream_t stream) {
  const float* input_sequence = (const float*)d_in[0];  // (4,1,1024,1,4096)
  // d_in[1] = hiddens (unused)
  const float* Lambda_re = (const float*)d_in[2];
  const float* Lambda_im = (const float*)d_in[3];
  const float* B         = (const float*)d_in[4];       // (512,1024,2)
  const float* C         = (const float*)d_in[5];       // (1024,512,2)
  const float* D         = (const float*)d_in[6];       // (1024,)
  const float* log_step  = (const float*)d_in[7];       // (512,1)
  float* out = (float*)d_out;

  float2* ws = (float2*)d_ws;
  float2* Bbar = ws + BBAR_OFF;
  float2* Lbar = ws + LBAR_OFF;
  float2* Bu   = ws + BU_OFF;

  k_precompute<<<dim3(kP), 256, 0, stream>>>(Lambda_re, Lambda_im, B, log_step, ws);
  k_gemm1<<<dim3(kL / 64, kP / 64, kB), 256, 0, stream>>>(Bbar, input_sequence, Bu);
  k_scan<<<dim3(kB * kP), 256, 0, stream>>>(Bu, Lbar);
  k_gemm2<<<dim3(kL / 64, kH / 64, kB), 256, 0, stream>>>(
      (const float2*)C, (const float2*)Bu, input_sequence, D, out);
}

// Round 2
// 437.837 us; speedup vs baseline: 2.4108x; 2.4108x over previous
//
#include <hip/hip_runtime.h>
#include <math.h>

// S5 SSM forward — MFMA split-bf16 path.
// BSZ=4, L=4096, H=1024, P=512.
// Pipeline: prep(A1=[Bbar_re;Bbar_im], A2=[2Cr|-2Ci], Lambda_bar)
//   -> transpose+split u[b][h][l] -> uT hi/lo [b][l][h]
//   -> GEMM1 (MFMA, 3-term split): Bu[b][m][l], m = p (re) / 512+p (im), fp32
//   -> scan (fp32, planar, in-place)
//   -> transpose+split xs -> xsT hi/lo [b][l][k']
//   -> GEMM2 (MFMA) + D*u + exact GeLU -> out[b][h][l] fp32

constexpr int kB = 4, kL = 4096, kH = 1024, kP = 512;
constexpr int kM = 1024, kK = 1024, kN = 4096;

typedef short bf16x8 __attribute__((ext_vector_type(8)));
typedef float f32x4 __attribute__((ext_vector_type(4)));

// ---- ws layout (bytes), MFMA path
constexpr size_t A1H_OFF = 0;
constexpr size_t A1L_OFF = A1H_OFF + (size_t)kM * kK * 2;
constexpr size_t A2H_OFF = A1L_OFF + (size_t)kM * kK * 2;
constexpr size_t A2L_OFF = A2H_OFF + (size_t)kM * kK * 2;
constexpr size_t LBAR_B  = A2L_OFF + (size_t)kM * kK * 2;      // 512 float2
constexpr size_t BU_B    = (LBAR_B + 8192 + 255) & ~(size_t)255;
constexpr size_t TH_B    = BU_B + (size_t)kB * kM * kN * 4;    // fp32 Bu/xs
constexpr size_t TL_B    = TH_B + (size_t)kB * kN * kK * 2;    // bf16 hi plane
constexpr size_t FULL_BYTES = TL_B + (size_t)kB * kN * kK * 2; // + lo plane
constexpr size_t MID_BYTES  = TL_B;

// ---- bf16 helpers
__device__ __forceinline__ unsigned short f2bf(float x) {
  unsigned int u = __float_as_uint(x);
  u += 0x7fffu + ((u >> 16) & 1u);
  return (unsigned short)(u >> 16);
}
__device__ __forceinline__ float bf2f(unsigned short h) {
  return __uint_as_float(((unsigned int)h) << 16);
}

__device__ __forceinline__ void gl2lds16(const void* g, void* l) {
  __builtin_amdgcn_global_load_lds(
      (const __attribute__((address_space(1))) void*)g,
      (__attribute__((address_space(3))) void*)l, 16, 0, 0);
}

// ---------------------------------------------------------------- prep1
// Lambda_bar + A1 = [Bbar_re ; Bbar_im] as bf16 hi/lo, rows p and 512+p.
__global__ __launch_bounds__(256) void k_prep1(
    const float* __restrict__ Lre, const float* __restrict__ Lim,
    const float* __restrict__ B, const float* __restrict__ log_step,
    unsigned char* __restrict__ ws) {
  int p = blockIdx.x;
  float lr = Lre[p], li = Lim[p];
  float step = expf(log_step[p]);
  float er = expf(lr * step);
  float sb, cb;
  sincosf(li * step, &sb, &cb);
  float lbr = er * cb, lbi = er * sb;
  float nr = lbr - 1.0f, ni = lbi;
  float inv = 1.0f / (lr * lr + li * li);
  float sr = (nr * lr + ni * li) * inv;
  float si = (ni * lr - nr * li) * inv;

  if (threadIdx.x == 0) ((float2*)(ws + LBAR_B))[p] = make_float2(lbr, lbi);

  unsigned short* a1h = (unsigned short*)(ws + A1H_OFF);
  unsigned short* a1l = (unsigned short*)(ws + A1L_OFF);
  const float* Brow = B + (size_t)p * kH * 2;
  for (int h = threadIdx.x; h < kH; h += 256) {
    float br = Brow[2 * h], bi = Brow[2 * h + 1];
    float re = sr * br - si * bi;
    float im = sr * bi + si * br;
    unsigned short rh = f2bf(re), ih = f2bf(im);
    a1h[(size_t)p * kK + h] = rh;
    a1l[(size_t)p * kK + h] = f2bf(re - bf2f(rh));
    a1h[(size_t)(kP + p) * kK + h] = ih;
    a1l[(size_t)(kP + p) * kK + h] = f2bf(im - bf2f(ih));
  }
}

// ---------------------------------------------------------------- prep2
// A2[h][k] = 2*Cr[h][k] (k<512) | -2*Ci[h][k-512]  (2.0 and sign folded in).
__global__ __launch_bounds__(256) void k_prep2(
    const float* __restrict__ C, unsigned char* __restrict__ ws) {
  int h = blockIdx.x;
  unsigned short* a2h = (unsigned short*)(ws + A2H_OFF);
  unsigned short* a2l = (unsigned short*)(ws + A2L_OFF);
  for (int k = threadIdx.x; k < kK; k += 256) {
    float v = (k < kP) ? 2.f * C[((size_t)h * kP + k) * 2]
                       : -2.f * C[((size_t)h * kP + (k - kP)) * 2 + 1];
    unsigned short hi = f2bf(v);
    a2h[(size_t)h * kK + k] = hi;
    a2l[(size_t)h * kK + k] = f2bf(v - bf2f(hi));
  }
}

// ---------------------------------------------------------------- transpose
// in: fp32 [b][1024][4096] -> out: bf16 hi(/lo) [b][4096][1024]
template <bool WLO>
__global__ __launch_bounds__(256) void k_transpose(
    const float* __restrict__ in, unsigned short* __restrict__ oh,
    unsigned short* __restrict__ ol) {
  __shared__ float t[64][65];
  int b = blockIdx.z;
  int r0 = blockIdx.y * 64;  // input row block (h / k')
  int c0 = blockIdx.x * 64;  // input col block (l)
  int tid = threadIdx.x;
  const float* src = in + ((size_t)b * 1024 + r0) * 4096 + c0;
  int cc = (tid & 15) * 4, rr = tid >> 4;
#pragma unroll
  for (int i = 0; i < 4; i++) {
    float4 v = *(const float4*)(src + (size_t)(rr + i * 16) * 4096 + cc);
    t[rr + i * 16][cc + 0] = v.x;
    t[rr + i * 16][cc + 1] = v.y;
    t[rr + i * 16][cc + 2] = v.z;
    t[rr + i * 16][cc + 3] = v.w;
  }
  __syncthreads();
  int oc = tid >> 2;        // 0..63 : output row within tile (= l index)
  int og = (tid & 3) * 2;   // two 8-wide groups along output cols (= r)
#pragma unroll
  for (int i = 0; i < 2; i++) {
    int g = og + i;
    unsigned short hv[8], lv[8];
#pragma unroll
    for (int j = 0; j < 8; j++) {
      float x = t[g * 8 + j][oc];
      unsigned short h16 = f2bf(x);
      hv[j] = h16;
      if (WLO) lv[j] = f2bf(x - bf2f(h16));
    }
    size_t ob = ((size_t)b * 4096 + c0 + oc) * 1024 + r0 + g * 8;
    *(uint4*)(oh + ob) = *(uint4*)hv;
    if (WLO) *(uint4*)(ol + ob) = *(uint4*)lv;
  }
}

// ---------------------------------------------------------------- GEMM
// out[b][m][n] = sum_k A[m][k] * Bm[b][n][k]  (A,Bm bf16 hi/lo split)
// TERMS=3: ah*bh + al*bh + ah*bl ; TERMS=2: (ah+al)*bh
// EPI: y = acc + D[m]*u[b][m][n]; gelu(y)
template <int TERMS, bool EPI>
__global__ __launch_bounds__(256) void k_gemm(
    const unsigned short* __restrict__ Ah, const unsigned short* __restrict__ Al,
    const unsigned short* __restrict__ Bh, const unsigned short* __restrict__ Bl,
    float* __restrict__ out, const float* __restrict__ u,
    const float* __restrict__ D) {
  __shared__ unsigned short sAh[128 * 32], sAl[128 * 32];
  __shared__ unsigned short sBh[128 * 32], sBl[128 * 32];
  int b = blockIdx.z;
  int m0 = blockIdx.y * 128, n0 = blockIdx.x * 128;
  int tid = threadIdx.x, lane = tid & 63, w = tid >> 6;
  int wm = (w & 1) * 64, wn = (w >> 1) * 64;
  int quad = lane >> 4, r = lane & 15;

  f32x4 acc[4][4] = {};

  const size_t bstride = (size_t)b * kN * kK;

  for (int k0 = 0; k0 < kK; k0 += 32) {
#pragma unroll
    for (int pass = 0; pass < 2; pass++) {
      int c = tid + pass * 256;             // chunk 0..511
      int row = c >> 2;
      int kg = (c & 3) ^ (row & 3);         // bank swizzle (global side only)
      size_t ga = (size_t)(m0 + row) * kK + k0 + kg * 8;
      size_t gb = bstride + (size_t)(n0 + row) * kK + k0 + kg * 8;
      gl2lds16(Ah + ga, sAh + c * 8);
      gl2lds16(Al + ga, sAl + c * 8);
      gl2lds16(Bh + gb, sBh + c * 8);
      if (TERMS == 3) gl2lds16(Bl + gb, sBl + c * 8);
    }
    __syncthreads();

    bf16x8 ah[4], al[4];
#pragma unroll
    for (int mi = 0; mi < 4; mi++) {
      int R = wm + mi * 16 + r;
      int ch = R * 4 + (quad ^ (R & 3));
      ah[mi] = ((const bf16x8*)sAh)[ch];
      al[mi] = ((const bf16x8*)sAl)[ch];
    }
#pragma unroll
    for (int ni = 0; ni < 4; ni++) {
      int R = wn + ni * 16 + r;
      int ch = R * 4 + (quad ^ (R & 3));
      bf16x8 bh = ((const bf16x8*)sBh)[ch];
      bf16x8 bl = (TERMS == 3) ? ((const bf16x8*)sBl)[ch] : bh;
#pragma unroll
      for (int mi = 0; mi < 4; mi++) {
        acc[mi][ni] = __builtin_amdgcn_mfma_f32_16x16x32_bf16(ah[mi], bh, acc[mi][ni], 0, 0, 0);
        acc[mi][ni] = __builtin_amdgcn_mfma_f32_16x16x32_bf16(al[mi], bh, acc[mi][ni], 0, 0, 0);
        if (TERMS == 3)
          acc[mi][ni] = __builtin_amdgcn_mfma_f32_16x16x32_bf16(ah[mi], bl, acc[mi][ni], 0, 0, 0);
      }
    }
    __syncthreads();
  }

  // C/D layout: col = lane&15, row = quad*4 + reg  [m89/m91 verified]
#pragma unroll
  for (int mi = 0; mi < 4; mi++) {
#pragma unroll
    for (int reg = 0; reg < 4; reg++) {
      int row = m0 + wm + mi * 16 + quad * 4 + reg;
      float dv = EPI ? D[row] : 0.f;
#pragma unroll
      for (int ni = 0; ni < 4; ni++) {
        int col = n0 + wn + ni * 16 + r;
        size_t o = ((size_t)b * kM + row) * (size_t)kN + col;
        float v = acc[mi][ni][reg];
        if (EPI) {
          float y = v + dv * u[o];
          v = 0.5f * y * (1.f + erff(y * 0.70710678118654752f));
        }
        out[o] = v;
      }
    }
  }
}

// ---------------------------------------------------------------- scan (planar)
__global__ __launch_bounds__(256) void k_scan(float* __restrict__ bu,
                                              const float2* __restrict__ lbar) {
  int p = blockIdx.x & (kP - 1);
  int b = blockIdx.x >> 9;
  int tid = threadIdx.x, lane = tid & 63, w = tid >> 6;
  float2 lam = lbar[p];
  float* sre = bu + ((size_t)b * kM + p) * (size_t)kN;
  float* sim = sre + (size_t)kP * kN;

  float vr[16], vi[16];
  {
    const float4* pr = (const float4*)(sre + tid * 16);
    const float4* pi = (const float4*)(sim + tid * 16);
#pragma unroll
    for (int i = 0; i < 4; i++) {
      float4 a = pr[i], c = pi[i];
      vr[4 * i] = a.x; vr[4 * i + 1] = a.y; vr[4 * i + 2] = a.z; vr[4 * i + 3] = a.w;
      vi[4 * i] = c.x; vi[4 * i + 1] = c.y; vi[4 * i + 2] = c.z; vi[4 * i + 3] = c.w;
    }
  }

  float xr = 0.f, xi = 0.f;
#pragma unroll
  for (int i = 0; i < 16; i++) {
    float nr2 = fmaf(lam.x, xr, fmaf(-lam.y, xi, vr[i]));
    float ni2 = fmaf(lam.x, xi, fmaf(lam.y, xr, vi[i]));
    xr = nr2; xi = ni2;
  }

  float Ar = lam.x, Ai = lam.y;
#pragma unroll
  for (int s = 0; s < 4; s++) {
    float tr = Ar * Ar - Ai * Ai, ti = 2.f * Ar * Ai;
    Ar = tr; Ai = ti;
  }
  float br = xr, bi = xi;

  for (int off = 1; off < 64; off <<= 1) {
    float pAr = __shfl_up(Ar, off), pAi = __shfl_up(Ai, off);
    float pbr = __shfl_up(br, off), pbi = __shfl_up(bi, off);
    if (lane >= off) {
      float nAr = Ar * pAr - Ai * pAi;
      float nAi = Ar * pAi + Ai * pAr;
      float nbr = Ar * pbr - Ai * pbi + br;
      float nbi = Ar * pbi + Ai * pbr + bi;
      Ar = nAr; Ai = nAi; br = nbr; bi = nbi;
    }
  }

  __shared__ float4 wtot[4];
  if (lane == 63) wtot[w] = make_float4(Ar, Ai, br, bi);
  __syncthreads();

  float eAr = __shfl_up(Ar, 1), eAi = __shfl_up(Ai, 1);
  float ebr = __shfl_up(br, 1), ebi = __shfl_up(bi, 1);
  if (lane == 0) { eAr = 1.f; eAi = 0.f; ebr = 0.f; ebi = 0.f; }

  float pAr = 1.f, pAi = 0.f, pbr = 0.f, pbi = 0.f;
  for (int j = 0; j < w; j++) {
    float4 t = wtot[j];
    float nAr = t.x * pAr - t.y * pAi;
    float nAi = t.x * pAi + t.y * pAr;
    float nbr = t.x * pbr - t.y * pbi + t.z;
    float nbi = t.x * pbi + t.y * pbr + t.w;
    pAr = nAr; pAi = nAi; pbr = nbr; pbi = nbi;
  }

  float initr = eAr * pbr - eAi * pbi + ebr;
  float initi = eAr * pbi + eAi * pbr + ebi;

  xr = initr; xi = initi;
  float4* qr = (float4*)(sre + tid * 16);
  float4* qi = (float4*)(sim + tid * 16);
#pragma unroll
  for (int i = 0; i < 4; i++) {
    float rr[4], ii[4];
#pragma unroll
    for (int j = 0; j < 4; j++) {
      float nr2 = fmaf(lam.x, xr, fmaf(-lam.y, xi, vr[4 * i + j]));
      float ni2 = fmaf(lam.x, xi, fmaf(lam.y, xr, vi[4 * i + j]));
      xr = nr2; xi = ni2; rr[j] = nr2; ii[j] = ni2;
    }
    qr[i] = make_float4(rr[0], rr[1], rr[2], rr[3]);
    qi[i] = make_float4(ii[0], ii[1], ii[2], ii[3]);
  }
}

// ================================================================ fp32 fallback
// (round-1 proven path; used only if ws_size < MID_BYTES)
constexpr size_t OBBAR = 0;
constexpr size_t OLBAR = (size_t)kP * kH;
constexpr size_t OBU = OLBAR + 1024;

__global__ __launch_bounds__(256) void k_precomputeF(
    const float* __restrict__ Lre, const float* __restrict__ Lim,
    const float* __restrict__ B, const float* __restrict__ log_step,
    float2* __restrict__ ws) {
  int p = blockIdx.x;
  float lr = Lre[p], li = Lim[p];
  float step = expf(log_step[p]);
  float er = expf(lr * step);
  float sb, cb;
  sincosf(li * step, &sb, &cb);
  float lbr = er * cb, lbi = er * sb;
  float nr = lbr - 1.0f, ni = lbi;
  float inv = 1.0f / (lr * lr + li * li);
  float sr = (nr * lr + ni * li) * inv;
  float si = (ni * lr - nr * li) * inv;
  if (threadIdx.x == 0) ws[OLBAR + p] = make_float2(lbr, lbi);
  float2* Bbar = ws + OBBAR;
  const float* Brow = B + (size_t)p * kH * 2;
  for (int h = threadIdx.x; h < kH; h += 256) {
    float br = Brow[2 * h], bi = Brow[2 * h + 1];
    Bbar[(size_t)p * kH + h] = make_float2(sr * br - si * bi, sr * bi + si * br);
  }
}

__global__ __launch_bounds__(256) void k_gemm1F(
    const float2* __restrict__ ws_bbar, const float* __restrict__ u,
    float2* __restrict__ Bu) {
  __shared__ float2 As[16][64];
  __shared__ float Bs[16][64];
  int b = blockIdx.z, m0 = blockIdx.y * 64, n0 = blockIdx.x * 64;
  int tid = threadIdx.x, tn = tid & 15, tm = tid >> 4;
  const float* uB = u + (size_t)b * kH * kL;
  float2 acc[4][4];
#pragma unroll
  for (int i = 0; i < 4; i++)
#pragma unroll
    for (int j = 0; j < 4; j++) acc[i][j] = make_float2(0.f, 0.f);
  int ar = tid >> 2, ac = (tid & 3) * 4, bk = tid >> 4, bc = (tid & 15) * 4;
  for (int k0 = 0; k0 < kH; k0 += 16) {
    const float4* src = (const float4*)(ws_bbar + (size_t)(m0 + ar) * kH + k0 + ac);
    float4 v01 = src[0], v23 = src[1];
    As[ac + 0][ar] = make_float2(v01.x, v01.y);
    As[ac + 1][ar] = make_float2(v01.z, v01.w);
    As[ac + 2][ar] = make_float2(v23.x, v23.y);
    As[ac + 3][ar] = make_float2(v23.z, v23.w);
    float4 v = *(const float4*)(uB + (size_t)(k0 + bk) * kL + n0 + bc);
    *(float4*)&Bs[bk][bc] = v;
    __syncthreads();
#pragma unroll
    for (int kk = 0; kk < 16; ++kk) {
      const float4* arow = (const float4*)&As[kk][0];
      float4 a01 = arow[tm * 2 + 0], a23 = arow[tm * 2 + 1];
      float2 a[4] = {make_float2(a01.x, a01.y), make_float2(a01.z, a01.w),
                     make_float2(a23.x, a23.y), make_float2(a23.z, a23.w)};
      float4 bv = ((const float4*)&Bs[kk][0])[tn];
      float bb[4] = {bv.x, bv.y, bv.z, bv.w};
#pragma unroll
      for (int mi = 0; mi < 4; mi++)
#pragma unroll
        for (int ni = 0; ni < 4; ni++) {
          acc[mi][ni].x = fmaf(a[mi].x, bb[ni], acc[mi][ni].x);
          acc[mi][ni].y = fmaf(a[mi].y, bb[ni], acc[mi][ni].y);
        }
    }
    __syncthreads();
  }
  float2* BuB = Bu + (size_t)b * kP * kL;
#pragma unroll
  for (int mi = 0; mi < 4; mi++) {
    int row = m0 + tm * 4 + mi;
    float2* dst = BuB + (size_t)row * kL + n0 + tn * 4;
    ((float4*)dst)[0] = make_float4(acc[mi][0].x, acc[mi][0].y, acc[mi][1].x, acc[mi][1].y);
    ((float4*)dst)[1] = make_float4(acc[mi][2].x, acc[mi][2].y, acc[mi][3].x, acc[mi][3].y);
  }
}

__global__ __launch_bounds__(256) void k_scanF(float2* __restrict__ Bu,
                                               const float2* __restrict__ Lbar) {
  int p = blockIdx.x & (kP - 1);
  int b = blockIdx.x >> 9;
  int tid = threadIdx.x, lane = tid & 63, w = tid >> 6;
  float2 lam = Lbar[p];
  float2* seq = Bu + ((size_t)b * kP + p) * kL;
  float2 v[16];
  const float4* src = (const float4*)(seq + tid * 16);
#pragma unroll
  for (int i = 0; i < 8; i++) {
    float4 t = src[i];
    v[2 * i] = make_float2(t.x, t.y);
    v[2 * i + 1] = make_float2(t.z, t.w);
  }
  float xr = 0.f, xi = 0.f;
#pragma unroll
  for (int i = 0; i < 16; i++) {
    float nr2 = fmaf(lam.x, xr, fmaf(-lam.y, xi, v[i].x));
    float ni2 = fmaf(lam.x, xi, fmaf(lam.y, xr, v[i].y));
    xr = nr2; xi = ni2;
  }
  float Ar = lam.x, Ai = lam.y;
#pragma unroll
  for (int s = 0; s < 4; s++) {
    float tr = Ar * Ar - Ai * Ai, ti = 2.f * Ar * Ai;
    Ar = tr; Ai = ti;
  }
  float br = xr, bi = xi;
  for (int off = 1; off < 64; off <<= 1) {
    float pAr = __shfl_up(Ar, off), pAi = __shfl_up(Ai, off);
    float pbr = __shfl_up(br, off), pbi = __shfl_up(bi, off);
    if (lane >= off) {
      float nAr = Ar * pAr - Ai * pAi, nAi = Ar * pAi + Ai * pAr;
      float nbr = Ar * pbr - Ai * pbi + br, nbi = Ar * pbi + Ai * pbr + bi;
      Ar = nAr; Ai = nAi; br = nbr; bi = nbi;
    }
  }
  __shared__ float4 wtot[4];
  if (lane == 63) wtot[w] = make_float4(Ar, Ai, br, bi);
  __syncthreads();
  float eAr = __shfl_up(Ar, 1), eAi = __shfl_up(Ai, 1);
  float ebr = __shfl_up(br, 1), ebi = __shfl_up(bi, 1);
  if (lane == 0) { eAr = 1.f; eAi = 0.f; ebr = 0.f; ebi = 0.f; }
  float pAr = 1.f, pAi = 0.f, pbr = 0.f, pbi = 0.f;
  for (int j = 0; j < w; j++) {
    float4 t = wtot[j];
    float nAr = t.x * pAr - t.y * pAi, nAi = t.x * pAi + t.y * pAr;
    float nbr = t.x * pbr - t.y * pbi + t.z, nbi = t.x * pbi + t.y * pbr + t.w;
    pAr = nAr; pAi = nAi; pbr = nbr; pbi = nbi;
  }
  float initr = eAr * pbr - eAi * pbi + ebr;
  float initi = eAr * pbi + eAi * pbr + ebi;
  xr = initr; xi = initi;
  float4* dst = (float4*)(seq + tid * 16);
#pragma unroll
  for (int i = 0; i < 8; i++) {
    float nr0 = fmaf(lam.x, xr, fmaf(-lam.y, xi, v[2 * i].x));
    float ni0 = fmaf(lam.x, xi, fmaf(lam.y, xr, v[2 * i].y));
    float nr1 = fmaf(lam.x, nr0, fmaf(-lam.y, ni0, v[2 * i + 1].x));
    float ni1 = fmaf(lam.x, ni0, fmaf(lam.y, nr0, v[2 * i + 1].y));
    dst[i] = make_float4(nr0, ni0, nr1, ni1);
    xr = nr1; xi = ni1;
  }
}

__global__ __launch_bounds__(256) void k_gemm2F(
    const float2* __restrict__ C, const float2* __restrict__ X,
    const float* __restrict__ u, const float* __restrict__ D,
    float* __restrict__ out) {
  __shared__ float2 As[16][64];
  __shared__ float2 Bs[16][64];
  int b = blockIdx.z, m0 = blockIdx.y * 64, n0 = blockIdx.x * 64;
  int tid = threadIdx.x, tn = tid & 15, tm = tid >> 4;
  const float2* Xb = X + (size_t)b * kP * kL;
  float acc[4][4];
#pragma unroll
  for (int i = 0; i < 4; i++)
#pragma unroll
    for (int j = 0; j < 4; j++) acc[i][j] = 0.f;
  int ar = tid >> 2, ac = (tid & 3) * 4, bk = tid >> 4, bc = (tid & 15) * 4;
  for (int k0 = 0; k0 < kP; k0 += 16) {
    const float4* src = (const float4*)(C + (size_t)(m0 + ar) * kP + k0 + ac);
    float4 v01 = src[0], v23 = src[1];
    As[ac + 0][ar] = make_float2(v01.x, v01.y);
    As[ac + 1][ar] = make_float2(v01.z, v01.w);
    As[ac + 2][ar] = make_float2(v23.x, v23.y);
    As[ac + 3][ar] = make_float2(v23.z, v23.w);
    const float4* srcb = (const float4*)(Xb + (size_t)(k0 + bk) * kL + n0 + bc);
    ((float4*)&Bs[bk][bc])[0] = srcb[0];
    ((float4*)&Bs[bk][bc])[1] = srcb[1];
    __syncthreads();
#pragma unroll
    for (int kk = 0; kk < 16; ++kk) {
      const float4* arow = (const float4*)&As[kk][0];
      float4 a01 = arow[tm * 2 + 0], a23 = arow[tm * 2 + 1];
      float2 a[4] = {make_float2(a01.x, a01.y), make_float2(a01.z, a01.w),
                     make_float2(a23.x, a23.y), make_float2(a23.z, a23.w)};
      const float4* brow = (const float4*)&Bs[kk][0];
      float4 b01 = brow[tn * 2 + 0], b23 = brow[tn * 2 + 1];
      float2 bb[4] = {make_float2(b01.x, b01.y), make_float2(b01.z, b01.w),
                      make_float2(b23.x, b23.y), make_float2(b23.z, b23.w)};
#pragma unroll
      for (int mi = 0; mi < 4; mi++)
#pragma unroll
        for (int ni = 0; ni < 4; ni++) {
          acc[mi][ni] = fmaf(a[mi].x, bb[ni].x, acc[mi][ni]);
          acc[mi][ni] = fmaf(-a[mi].y, bb[ni].y, acc[mi][ni]);
        }
    }
    __syncthreads();
  }
#pragma unroll
  for (int mi = 0; mi < 4; mi++) {
    int h = m0 + tm * 4 + mi;
    float d = D[h];
    const float* urow = u + ((size_t)b * kH + h) * kL + n0 + tn * 4;
    float4 uv = *(const float4*)urow;
    float uu[4] = {uv.x, uv.y, uv.z, uv.w};
    float res[4];
#pragma unroll
    for (int ni = 0; ni < 4; ni++) {
      float y = 2.f * acc[mi][ni] + d * uu[ni];
      res[ni] = 0.5f * y * (1.f + erff(y * 0.70710678118654752f));
    }
    float* orow = out + ((size_t)b * kH + h) * kL + n0 + tn * 4;
    *(float4*)orow = make_float4(res[0], res[1], res[2], res[3]);
  }
}

// ---------------------------------------------------------------- launch
extern "C" void kernel_launch(void* const* d_in, const int* in_sizes, int n_in,
                              void* d_out, int out_size, void* d_ws, size_t ws_size,
                              hipStream_t stream) {
  const float* input_sequence = (const float*)d_in[0];
  const float* Lambda_re = (const float*)d_in[2];
  const float* Lambda_im = (const float*)d_in[3];
  const float* B = (const float*)d_in[4];
  const float* C = (const float*)d_in[5];
  const float* D = (const float*)d_in[6];
  const float* log_step = (const float*)d_in[7];
  float* out = (float*)d_out;

  if (ws_size >= MID_BYTES) {
    unsigned char* ws = (unsigned char*)d_ws;
    unsigned short* a1h = (unsigned short*)(ws + A1H_OFF);
    unsigned short* a1l = (unsigned short*)(ws + A1L_OFF);
    unsigned short* a2h = (unsigned short*)(ws + A2H_OFF);
    unsigned short* a2l = (unsigned short*)(ws + A2L_OFF);
    float2* lbar = (float2*)(ws + LBAR_B);
    float* bu = (float*)(ws + BU_B);
    unsigned short* th = (unsigned short*)(ws + TH_B);
    unsigned short* tl = (unsigned short*)(ws + TL_B);
    bool full = ws_size >= FULL_BYTES;

    k_prep1<<<dim3(kP), 256, 0, stream>>>(Lambda_re, Lambda_im, B, log_step, ws);
    k_prep2<<<dim3(kH), 256, 0, stream>>>(C, ws);

    dim3 tgrid(kL / 64, 1024 / 64, kB);
    dim3 ggrid(kN / 128, kM / 128, kB);

    if (full) {
      k_transpose<true><<<tgrid, 256, 0, stream>>>(input_sequence, th, tl);
      k_gemm<3, false><<<ggrid, 256, 0, stream>>>(a1h, a1l, th, tl, bu, nullptr, nullptr);
      k_scan<<<dim3(kB * kP), 256, 0, stream>>>(bu, lbar);
      k_transpose<true><<<tgrid, 256, 0, stream>>>(bu, th, tl);
      k_gemm<3, true><<<ggrid, 256, 0, stream>>>(a2h, a2l, th, tl, out, input_sequence, D);
    } else {
      k_transpose<false><<<tgrid, 256, 0, stream>>>(input_sequence, th, th);
      k_gemm<2, false><<<ggrid, 256, 0, stream>>>(a1h, a1l, th, th, bu, nullptr, nullptr);
      k_scan<<<dim3(kB * kP), 256, 0, stream>>>(bu, lbar);
      k_transpose<false><<<tgrid, 256, 0, stream>>>(bu, th, th);
      k_gemm<2, true><<<ggrid, 256, 0, stream>>>(a2h, a2l, th, th, out, input_sequence, D);
    }
  } else {
    // fp32 fallback (round-1 path)
    float2* ws = (float2*)d_ws;
    float2* Bbar = ws + OBBAR;
    float2* Lbar = ws + OLBAR;
    float2* Bu = ws + OBU;
    k_precomputeF<<<dim3(kP), 256, 0, stream>>>(Lambda_re, Lambda_im, B, log_step, ws);
    k_gemm1F<<<dim3(kL / 64, kP / 64, kB), 256, 0, stream>>>(Bbar, input_sequence, Bu);
    k_scanF<<<dim3(kB * kP), 256, 0, stream>>>(Bu, Lbar);
    k_gemm2F<<<dim3(kL / 64, kH / 64, kB), 256, 0, stream>>>(
        (const float2*)C, (const float2*)Bu, input_sequence, D, out);
  }
}

// Round 3
// 394.513 us; speedup vs baseline: 2.6755x; 1.1098x over previous
//
#include <hip/hip_runtime.h>
#include <math.h>

// S5 SSM forward — MFMA split-bf16 path, TERMS=2 (A=weights split hi/lo exact,
// B=data plain bf16). BSZ=4, L=4096, H=1024, P=512.
// prep(A1=[Bbar_re;Bbar_im], A2=[2Cr|-2Ci], Lambda_bar)
//   -> transpose u[b][h][l] -> uT bf16 [b][l][h]
//   -> GEMM1 (MFMA, 2-term): Bu[b][m][l] fp32, m = p (re) / 512+p (im)
//   -> scan (fp32, planar, in-place)
//   -> transpose xs -> xsT bf16 [b][l][k']
//   -> GEMM2 (MFMA, 2-term) + D*u + exact GeLU -> out[b][h][l] fp32

constexpr int kB = 4, kL = 4096, kH = 1024, kP = 512;
constexpr int kM = 1024, kK = 1024, kN = 4096;

typedef short bf16x8 __attribute__((ext_vector_type(8)));
typedef float f32x4 __attribute__((ext_vector_type(4)));

// ---- ws layout (bytes), MFMA path
constexpr size_t A1H_OFF = 0;
constexpr size_t A1L_OFF = A1H_OFF + (size_t)kM * kK * 2;
constexpr size_t A2H_OFF = A1L_OFF + (size_t)kM * kK * 2;
constexpr size_t A2L_OFF = A2H_OFF + (size_t)kM * kK * 2;
constexpr size_t LBAR_B  = A2L_OFF + (size_t)kM * kK * 2;      // 512 float2
constexpr size_t BU_B    = (LBAR_B + 8192 + 255) & ~(size_t)255;
constexpr size_t TH_B    = BU_B + (size_t)kB * kM * kN * 4;    // fp32 Bu/xs
constexpr size_t MID_BYTES = TH_B + (size_t)kB * kN * kK * 2;  // + bf16 hi plane

// ---- bf16 helpers
__device__ __forceinline__ unsigned short f2bf(float x) {
  unsigned int u = __float_as_uint(x);
  u += 0x7fffu + ((u >> 16) & 1u);
  return (unsigned short)(u >> 16);
}
__device__ __forceinline__ float bf2f(unsigned short h) {
  return __uint_as_float(((unsigned int)h) << 16);
}

__device__ __forceinline__ void gl2lds16(const void* g, void* l) {
  __builtin_amdgcn_global_load_lds(
      (const __attribute__((address_space(1))) void*)g,
      (__attribute__((address_space(3))) void*)l, 16, 0, 0);
}

// ---------------------------------------------------------------- prep1
__global__ __launch_bounds__(256) void k_prep1(
    const float* __restrict__ Lre, const float* __restrict__ Lim,
    const float* __restrict__ B, const float* __restrict__ log_step,
    unsigned char* __restrict__ ws) {
  int p = blockIdx.x;
  float lr = Lre[p], li = Lim[p];
  float step = expf(log_step[p]);
  float er = expf(lr * step);
  float sb, cb;
  sincosf(li * step, &sb, &cb);
  float lbr = er * cb, lbi = er * sb;
  float nr = lbr - 1.0f, ni = lbi;
  float inv = 1.0f / (lr * lr + li * li);
  float sr = (nr * lr + ni * li) * inv;
  float si = (ni * lr - nr * li) * inv;

  if (threadIdx.x == 0) ((float2*)(ws + LBAR_B))[p] = make_float2(lbr, lbi);

  unsigned short* a1h = (unsigned short*)(ws + A1H_OFF);
  unsigned short* a1l = (unsigned short*)(ws + A1L_OFF);
  const float* Brow = B + (size_t)p * kH * 2;
  for (int h = threadIdx.x; h < kH; h += 256) {
    float br = Brow[2 * h], bi = Brow[2 * h + 1];
    float re = sr * br - si * bi;
    float im = sr * bi + si * br;
    unsigned short rh = f2bf(re), ih = f2bf(im);
    a1h[(size_t)p * kK + h] = rh;
    a1l[(size_t)p * kK + h] = f2bf(re - bf2f(rh));
    a1h[(size_t)(kP + p) * kK + h] = ih;
    a1l[(size_t)(kP + p) * kK + h] = f2bf(im - bf2f(ih));
  }
}

// ---------------------------------------------------------------- prep2
// A2[h][k] = 2*Cr[h][k] (k<512) | -2*Ci[h][k-512]
__global__ __launch_bounds__(256) void k_prep2(
    const float* __restrict__ C, unsigned char* __restrict__ ws) {
  int h = blockIdx.x;
  unsigned short* a2h = (unsigned short*)(ws + A2H_OFF);
  unsigned short* a2l = (unsigned short*)(ws + A2L_OFF);
  for (int k = threadIdx.x; k < kK; k += 256) {
    float v = (k < kP) ? 2.f * C[((size_t)h * kP + k) * 2]
                       : -2.f * C[((size_t)h * kP + (k - kP)) * 2 + 1];
    unsigned short hi = f2bf(v);
    a2h[(size_t)h * kK + k] = hi;
    a2l[(size_t)h * kK + k] = f2bf(v - bf2f(hi));
  }
}

// ---------------------------------------------------------------- transpose
// in: fp32 [b][1024][4096] -> out: bf16 hi [b][4096][1024]
__global__ __launch_bounds__(256) void k_transpose(
    const float* __restrict__ in, unsigned short* __restrict__ oh) {
  __shared__ float t[64][65];
  int b = blockIdx.z;
  int r0 = blockIdx.y * 64;
  int c0 = blockIdx.x * 64;
  int tid = threadIdx.x;
  const float* src = in + ((size_t)b * 1024 + r0) * 4096 + c0;
  int cc = (tid & 15) * 4, rr = tid >> 4;
#pragma unroll
  for (int i = 0; i < 4; i++) {
    float4 v = *(const float4*)(src + (size_t)(rr + i * 16) * 4096 + cc);
    t[rr + i * 16][cc + 0] = v.x;
    t[rr + i * 16][cc + 1] = v.y;
    t[rr + i * 16][cc + 2] = v.z;
    t[rr + i * 16][cc + 3] = v.w;
  }
  __syncthreads();
  int oc = tid >> 2;
  int og = (tid & 3) * 2;
#pragma unroll
  for (int i = 0; i < 2; i++) {
    int g = og + i;
    unsigned short hv[8];
#pragma unroll
    for (int j = 0; j < 8; j++) hv[j] = f2bf(t[g * 8 + j][oc]);
    size_t ob = ((size_t)b * 4096 + c0 + oc) * 1024 + r0 + g * 8;
    *(uint4*)(oh + ob) = *(uint4*)hv;
  }
}

// ---------------------------------------------------------------- GEMM
// out[b][m][n] = sum_k (Ah+Al)[m][k] * Bh[b][n][k]
// EPI: y = acc + D[m]*u[b][m][n]; gelu(y)
template <bool EPI>
__global__ __launch_bounds__(256) void k_gemm(
    const unsigned short* __restrict__ Ah, const unsigned short* __restrict__ Al,
    const unsigned short* __restrict__ Bh,
    float* __restrict__ out, const float* __restrict__ u,
    const float* __restrict__ D) {
  __shared__ unsigned short sAh[128 * 32], sAl[128 * 32], sBh[128 * 32];
  int b = blockIdx.z;
  int m0 = blockIdx.y * 128, n0 = blockIdx.x * 128;
  int tid = threadIdx.x, lane = tid & 63, w = tid >> 6;
  int wm = (w & 1) * 64, wn = (w >> 1) * 64;
  int quad = lane >> 4, r = lane & 15;

  f32x4 acc[4][4] = {};

  const size_t bstride = (size_t)b * kN * kK;

  for (int k0 = 0; k0 < kK; k0 += 32) {
#pragma unroll
    for (int pass = 0; pass < 2; pass++) {
      int c = tid + pass * 256;             // chunk 0..511
      int row = c >> 2;
      int kg = (c & 3) ^ (row & 3);         // bank swizzle (global side only)
      size_t ga = (size_t)(m0 + row) * kK + k0 + kg * 8;
      size_t gb = bstride + (size_t)(n0 + row) * kK + k0 + kg * 8;
      gl2lds16(Ah + ga, sAh + c * 8);
      gl2lds16(Al + ga, sAl + c * 8);
      gl2lds16(Bh + gb, sBh + c * 8);
    }
    __syncthreads();

    bf16x8 ah[4], al[4];
#pragma unroll
    for (int mi = 0; mi < 4; mi++) {
      int R = wm + mi * 16 + r;
      int ch = R * 4 + (quad ^ (R & 3));
      ah[mi] = ((const bf16x8*)sAh)[ch];
      al[mi] = ((const bf16x8*)sAl)[ch];
    }
#pragma unroll
    for (int ni = 0; ni < 4; ni++) {
      int R = wn + ni * 16 + r;
      int ch = R * 4 + (quad ^ (R & 3));
      bf16x8 bh = ((const bf16x8*)sBh)[ch];
#pragma unroll
      for (int mi = 0; mi < 4; mi++) {
        acc[mi][ni] = __builtin_amdgcn_mfma_f32_16x16x32_bf16(ah[mi], bh, acc[mi][ni], 0, 0, 0);
        acc[mi][ni] = __builtin_amdgcn_mfma_f32_16x16x32_bf16(al[mi], bh, acc[mi][ni], 0, 0, 0);
      }
    }
    __syncthreads();
  }

  // C/D layout: col = lane&15, row = quad*4 + reg
#pragma unroll
  for (int mi = 0; mi < 4; mi++) {
#pragma unroll
    for (int reg = 0; reg < 4; reg++) {
      int row = m0 + wm + mi * 16 + quad * 4 + reg;
      float dv = EPI ? D[row] : 0.f;
#pragma unroll
      for (int ni = 0; ni < 4; ni++) {
        int col = n0 + wn + ni * 16 + r;
        size_t o = ((size_t)b * kM + row) * (size_t)kN + col;
        float v = acc[mi][ni][reg];
        if (EPI) {
          float y = v + dv * u[o];
          v = 0.5f * y * (1.f + erff(y * 0.70710678118654752f));
        }
        out[o] = v;
      }
    }
  }
}

// ---------------------------------------------------------------- scan (planar)
__global__ __launch_bounds__(256) void k_scan(float* __restrict__ bu,
                                              const float2* __restrict__ lbar) {
  int p = blockIdx.x & (kP - 1);
  int b = blockIdx.x >> 9;
  int tid = threadIdx.x, lane = tid & 63, w = tid >> 6;
  float2 lam = lbar[p];
  float* sre = bu + ((size_t)b * kM + p) * (size_t)kN;
  float* sim = sre + (size_t)kP * kN;

  float vr[16], vi[16];
  {
    const float4* pr = (const float4*)(sre + tid * 16);
    const float4* pi = (const float4*)(sim + tid * 16);
#pragma unroll
    for (int i = 0; i < 4; i++) {
      float4 a = pr[i], c = pi[i];
      vr[4 * i] = a.x; vr[4 * i + 1] = a.y; vr[4 * i + 2] = a.z; vr[4 * i + 3] = a.w;
      vi[4 * i] = c.x; vi[4 * i + 1] = c.y; vi[4 * i + 2] = c.z; vi[4 * i + 3] = c.w;
    }
  }

  float xr = 0.f, xi = 0.f;
#pragma unroll
  for (int i = 0; i < 16; i++) {
    float nr2 = fmaf(lam.x, xr, fmaf(-lam.y, xi, vr[i]));
    float ni2 = fmaf(lam.x, xi, fmaf(lam.y, xr, vi[i]));
    xr = nr2; xi = ni2;
  }

  float Ar = lam.x, Ai = lam.y;
#pragma unroll
  for (int s = 0; s < 4; s++) {
    float tr = Ar * Ar - Ai * Ai, ti = 2.f * Ar * Ai;
    Ar = tr; Ai = ti;
  }
  float br = xr, bi = xi;

  for (int off = 1; off < 64; off <<= 1) {
    float pAr = __shfl_up(Ar, off), pAi = __shfl_up(Ai, off);
    float pbr = __shfl_up(br, off), pbi = __shfl_up(bi, off);
    if (lane >= off) {
      float nAr = Ar * pAr - Ai * pAi;
      float nAi = Ar * pAi + Ai * pAr;
      float nbr = Ar * pbr - Ai * pbi + br;
      float nbi = Ar * pbi + Ai * pbr + bi;
      Ar = nAr; Ai = nAi; br = nbr; bi = nbi;
    }
  }

  __shared__ float4 wtot[4];
  if (lane == 63) wtot[w] = make_float4(Ar, Ai, br, bi);
  __syncthreads();

  float eAr = __shfl_up(Ar, 1), eAi = __shfl_up(Ai, 1);
  float ebr = __shfl_up(br, 1), ebi = __shfl_up(bi, 1);
  if (lane == 0) { eAr = 1.f; eAi = 0.f; ebr = 0.f; ebi = 0.f; }

  float pAr = 1.f, pAi = 0.f, pbr = 0.f, pbi = 0.f;
  for (int j = 0; j < w; j++) {
    float4 t = wtot[j];
    float nAr = t.x * pAr - t.y * pAi;
    float nAi = t.x * pAi + t.y * pAr;
    float nbr = t.x * pbr - t.y * pbi + t.z;
    float nbi = t.x * pbi + t.y * pbr + t.w;
    pAr = nAr; pAi = nAi; pbr = nbr; pbi = nbi;
  }

  float initr = eAr * pbr - eAi * pbi + ebr;
  float initi = eAr * pbi + eAi * pbr + ebi;

  xr = initr; xi = initi;
  float4* qr = (float4*)(sre + tid * 16);
  float4* qi = (float4*)(sim + tid * 16);
#pragma unroll
  for (int i = 0; i < 4; i++) {
    float rr[4], ii[4];
#pragma unroll
    for (int j = 0; j < 4; j++) {
      float nr2 = fmaf(lam.x, xr, fmaf(-lam.y, xi, vr[4 * i + j]));
      float ni2 = fmaf(lam.x, xi, fmaf(lam.y, xr, vi[4 * i + j]));
      xr = nr2; xi = ni2; rr[j] = nr2; ii[j] = ni2;
    }
    qr[i] = make_float4(rr[0], rr[1], rr[2], rr[3]);
    qi[i] = make_float4(ii[0], ii[1], ii[2], ii[3]);
  }
}

// ================================================================ fp32 fallback
constexpr size_t OBBAR = 0;
constexpr size_t OLBAR = (size_t)kP * kH;
constexpr size_t OBU = OLBAR + 1024;

__global__ __launch_bounds__(256) void k_precomputeF(
    const float* __restrict__ Lre, const float* __restrict__ Lim,
    const float* __restrict__ B, const float* __restrict__ log_step,
    float2* __restrict__ ws) {
  int p = blockIdx.x;
  float lr = Lre[p], li = Lim[p];
  float step = expf(log_step[p]);
  float er = expf(lr * step);
  float sb, cb;
  sincosf(li * step, &sb, &cb);
  float lbr = er * cb, lbi = er * sb;
  float nr = lbr - 1.0f, ni = lbi;
  float inv = 1.0f / (lr * lr + li * li);
  float sr = (nr * lr + ni * li) * inv;
  float si = (ni * lr - nr * li) * inv;
  if (threadIdx.x == 0) ws[OLBAR + p] = make_float2(lbr, lbi);
  float2* Bbar = ws + OBBAR;
  const float* Brow = B + (size_t)p * kH * 2;
  for (int h = threadIdx.x; h < kH; h += 256) {
    float br = Brow[2 * h], bi = Brow[2 * h + 1];
    Bbar[(size_t)p * kH + h] = make_float2(sr * br - si * bi, sr * bi + si * br);
  }
}

__global__ __launch_bounds__(256) void k_gemm1F(
    const float2* __restrict__ ws_bbar, const float* __restrict__ u,
    float2* __restrict__ Bu) {
  __shared__ float2 As[16][64];
  __shared__ float Bs[16][64];
  int b = blockIdx.z, m0 = blockIdx.y * 64, n0 = blockIdx.x * 64;
  int tid = threadIdx.x, tn = tid & 15, tm = tid >> 4;
  const float* uB = u + (size_t)b * kH * kL;
  float2 acc[4][4];
#pragma unroll
  for (int i = 0; i < 4; i++)
#pragma unroll
    for (int j = 0; j < 4; j++) acc[i][j] = make_float2(0.f, 0.f);
  int ar = tid >> 2, ac = (tid & 3) * 4, bk = tid >> 4, bc = (tid & 15) * 4;
  for (int k0 = 0; k0 < kH; k0 += 16) {
    const float4* src = (const float4*)(ws_bbar + (size_t)(m0 + ar) * kH + k0 + ac);
    float4 v01 = src[0], v23 = src[1];
    As[ac + 0][ar] = make_float2(v01.x, v01.y);
    As[ac + 1][ar] = make_float2(v01.z, v01.w);
    As[ac + 2][ar] = make_float2(v23.x, v23.y);
    As[ac + 3][ar] = make_float2(v23.z, v23.w);
    float4 v = *(const float4*)(uB + (size_t)(k0 + bk) * kL + n0 + bc);
    *(float4*)&Bs[bk][bc] = v;
    __syncthreads();
#pragma unroll
    for (int kk = 0; kk < 16; ++kk) {
      const float4* arow = (const float4*)&As[kk][0];
      float4 a01 = arow[tm * 2 + 0], a23 = arow[tm * 2 + 1];
      float2 a[4] = {make_float2(a01.x, a01.y), make_float2(a01.z, a01.w),
                     make_float2(a23.x, a23.y), make_float2(a23.z, a23.w)};
      float4 bv = ((const float4*)&Bs[kk][0])[tn];
      float bb[4] = {bv.x, bv.y, bv.z, bv.w};
#pragma unroll
      for (int mi = 0; mi < 4; mi++)
#pragma unroll
        for (int ni = 0; ni < 4; ni++) {
          acc[mi][ni].x = fmaf(a[mi].x, bb[ni], acc[mi][ni].x);
          acc[mi][ni].y = fmaf(a[mi].y, bb[ni], acc[mi][ni].y);
        }
    }
    __syncthreads();
  }
  float2* BuB = Bu + (size_t)b * kP * kL;
#pragma unroll
  for (int mi = 0; mi < 4; mi++) {
    int row = m0 + tm * 4 + mi;
    float2* dst = BuB + (size_t)row * kL + n0 + tn * 4;
    ((float4*)dst)[0] = make_float4(acc[mi][0].x, acc[mi][0].y, acc[mi][1].x, acc[mi][1].y);
    ((float4*)dst)[1] = make_float4(acc[mi][2].x, acc[mi][2].y, acc[mi][3].x, acc[mi][3].y);
  }
}

__global__ __launch_bounds__(256) void k_scanF(float2* __restrict__ Bu,
                                               const float2* __restrict__ Lbar) {
  int p = blockIdx.x & (kP - 1);
  int b = blockIdx.x >> 9;
  int tid = threadIdx.x, lane = tid & 63, w = tid >> 6;
  float2 lam = Lbar[p];
  float2* seq = Bu + ((size_t)b * kP + p) * kL;
  float2 v[16];
  const float4* src = (const float4*)(seq + tid * 16);
#pragma unroll
  for (int i = 0; i < 8; i++) {
    float4 t = src[i];
    v[2 * i] = make_float2(t.x, t.y);
    v[2 * i + 1] = make_float2(t.z, t.w);
  }
  float xr = 0.f, xi = 0.f;
#pragma unroll
  for (int i = 0; i < 16; i++) {
    float nr2 = fmaf(lam.x, xr, fmaf(-lam.y, xi, v[i].x));
    float ni2 = fmaf(lam.x, xi, fmaf(lam.y, xr, v[i].y));
    xr = nr2; xi = ni2;
  }
  float Ar = lam.x, Ai = lam.y;
#pragma unroll
  for (int s = 0; s < 4; s++) {
    float tr = Ar * Ar - Ai * Ai, ti = 2.f * Ar * Ai;
    Ar = tr; Ai = ti;
  }
  float br = xr, bi = xi;
  for (int off = 1; off < 64; off <<= 1) {
    float pAr = __shfl_up(Ar, off), pAi = __shfl_up(Ai, off);
    float pbr = __shfl_up(br, off), pbi = __shfl_up(bi, off);
    if (lane >= off) {
      float nAr = Ar * pAr - Ai * pAi, nAi = Ar * pAi + Ai * pAr;
      float nbr = Ar * pbr - Ai * pbi + br, nbi = Ar * pbi + Ai * pbr + bi;
      Ar = nAr; Ai = nAi; br = nbr; bi = nbi;
    }
  }
  __shared__ float4 wtot[4];
  if (lane == 63) wtot[w] = make_float4(Ar, Ai, br, bi);
  __syncthreads();
  float eAr = __shfl_up(Ar, 1), eAi = __shfl_up(Ai, 1);
  float ebr = __shfl_up(br, 1), ebi = __shfl_up(bi, 1);
  if (lane == 0) { eAr = 1.f; eAi = 0.f; ebr = 0.f; ebi = 0.f; }
  float pAr = 1.f, pAi = 0.f, pbr = 0.f, pbi = 0.f;
  for (int j = 0; j < w; j++) {
    float4 t = wtot[j];
    float nAr = t.x * pAr - t.y * pAi, nAi = t.x * pAi + t.y * pAr;
    float nbr = t.x * pbr - t.y * pbi + t.z, nbi = t.x * pbi + t.y * pbr + t.w;
    pAr = nAr; pAi = nAi; pbr = nbr; pbi = nbi;
  }
  float initr = eAr * pbr - eAi * pbi + ebr;
  float initi = eAr * pbi + eAi * pbr + ebi;
  xr = initr; xi = initi;
  float4* dst = (float4*)(seq + tid * 16);
#pragma unroll
  for (int i = 0; i < 8; i++) {
    float nr0 = fmaf(lam.x, xr, fmaf(-lam.y, xi, v[2 * i].x));
    float ni0 = fmaf(lam.x, xi, fmaf(lam.y, xr, v[2 * i].y));
    float nr1 = fmaf(lam.x, nr0, fmaf(-lam.y, ni0, v[2 * i + 1].x));
    float ni1 = fmaf(lam.x, ni0, fmaf(lam.y, nr0, v[2 * i + 1].y));
    dst[i] = make_float4(nr0, ni0, nr1, ni1);
    xr = nr1; xi = ni1;
  }
}

__global__ __launch_bounds__(256) void k_gemm2F(
    const float2* __restrict__ C, const float2* __restrict__ X,
    const float* __restrict__ u, const float* __restrict__ D,
    float* __restrict__ out) {
  __shared__ float2 As[16][64];
  __shared__ float2 Bs[16][64];
  int b = blockIdx.z, m0 = blockIdx.y * 64, n0 = blockIdx.x * 64;
  int tid = threadIdx.x, tn = tid & 15, tm = tid >> 4;
  const float2* Xb = X + (size_t)b * kP * kL;
  float acc[4][4];
#pragma unroll
  for (int i = 0; i < 4; i++)
#pragma unroll
    for (int j = 0; j < 4; j++) acc[i][j] = 0.f;
  int ar = tid >> 2, ac = (tid & 3) * 4, bk = tid >> 4, bc = (tid & 15) * 4;
  for (int k0 = 0; k0 < kP; k0 += 16) {
    const float4* src = (const float4*)(C + (size_t)(m0 + ar) * kP + k0 + ac);
    float4 v01 = src[0], v23 = src[1];
    As[ac + 0][ar] = make_float2(v01.x, v01.y);
    As[ac + 1][ar] = make_float2(v01.z, v01.w);
    As[ac + 2][ar] = make_float2(v23.x, v23.y);
    As[ac + 3][ar] = make_float2(v23.z, v23.w);
    const float4* srcb = (const float4*)(Xb + (size_t)(k0 + bk) * kL + n0 + bc);
    ((float4*)&Bs[bk][bc])[0] = srcb[0];
    ((float4*)&Bs[bk][bc])[1] = srcb[1];
    __syncthreads();
#pragma unroll
    for (int kk = 0; kk < 16; ++kk) {
      const float4* arow = (const float4*)&As[kk][0];
      float4 a01 = arow[tm * 2 + 0], a23 = arow[tm * 2 + 1];
      float2 a[4] = {make_float2(a01.x, a01.y), make_float2(a01.z, a01.w),
                     make_float2(a23.x, a23.y), make_float2(a23.z, a23.w)};
      const float4* brow = (const float4*)&Bs[kk][0];
      float4 b01 = brow[tn * 2 + 0], b23 = brow[tn * 2 + 1];
      float2 bb[4] = {make_float2(b01.x, b01.y), make_float2(b01.z, b01.w),
                      make_float2(b23.x, b23.y), make_float2(b23.z, b23.w)};
#pragma unroll
      for (int mi = 0; mi < 4; mi++)
#pragma unroll
        for (int ni = 0; ni < 4; ni++) {
          acc[mi][ni] = fmaf(a[mi].x, bb[ni].x, acc[mi][ni]);
          acc[mi][ni] = fmaf(-a[mi].y, bb[ni].y, acc[mi][ni]);
        }
    }
    __syncthreads();
  }
#pragma unroll
  for (int mi = 0; mi < 4; mi++) {
    int h = m0 + tm * 4 + mi;
    float d = D[h];
    const float* urow = u + ((size_t)b * kH + h) * kL + n0 + tn * 4;
    float4 uv = *(const float4*)urow;
    float uu[4] = {uv.x, uv.y, uv.z, uv.w};
    float res[4];
#pragma unroll
    for (int ni = 0; ni < 4; ni++) {
      float y = 2.f * acc[mi][ni] + d * uu[ni];
      res[ni] = 0.5f * y * (1.f + erff(y * 0.70710678118654752f));
    }
    float* orow = out + ((size_t)b * kH + h) * kL + n0 + tn * 4;
    *(float4*)orow = make_float4(res[0], res[1], res[2], res[3]);
  }
}

// ---------------------------------------------------------------- launch
extern "C" void kernel_launch(void* const* d_in, const int* in_sizes, int n_in,
                              void* d_out, int out_size, void* d_ws, size_t ws_size,
                              hipStream_t stream) {
  const float* input_sequence = (const float*)d_in[0];
  const float* Lambda_re = (const float*)d_in[2];
  const float* Lambda_im = (const float*)d_in[3];
  const float* B = (const float*)d_in[4];
  const float* C = (const float*)d_in[5];
  const float* D = (const float*)d_in[6];
  const float* log_step = (const float*)d_in[7];
  float* out = (float*)d_out;

  if (ws_size >= MID_BYTES) {
    unsigned char* ws = (unsigned char*)d_ws;
    unsigned short* a1h = (unsigned short*)(ws + A1H_OFF);
    unsigned short* a1l = (unsigned short*)(ws + A1L_OFF);
    unsigned short* a2h = (unsigned short*)(ws + A2H_OFF);
    unsigned short* a2l = (unsigned short*)(ws + A2L_OFF);
    float2* lbar = (float2*)(ws + LBAR_B);
    float* bu = (float*)(ws + BU_B);
    unsigned short* th = (unsigned short*)(ws + TH_B);

    k_prep1<<<dim3(kP), 256, 0, stream>>>(Lambda_re, Lambda_im, B, log_step, ws);
    k_prep2<<<dim3(kH), 256, 0, stream>>>(C, ws);

    dim3 tgrid(kL / 64, 1024 / 64, kB);
    dim3 ggrid(kN / 128, kM / 128, kB);

    k_transpose<<<tgrid, 256, 0, stream>>>(input_sequence, th);
    k_gemm<false><<<ggrid, 256, 0, stream>>>(a1h, a1l, th, bu, nullptr, nullptr);
    k_scan<<<dim3(kB * kP), 256, 0, stream>>>(bu, lbar);
    k_transpose<<<tgrid, 256, 0, stream>>>(bu, th);
    k_gemm<true><<<ggrid, 256, 0, stream>>>(a2h, a2l, th, out, input_sequence, D);
  } else {
    // fp32 fallback (round-1 path)
    float2* ws = (float2*)d_ws;
    float2* Bbar = ws + OBBAR;
    float2* Lbar = ws + OLBAR;
    float2* Bu = ws + OBU;
    k_precomputeF<<<dim3(kP), 256, 0, stream>>>(Lambda_re, Lambda_im, B, log_step, ws);
    k_gemm1F<<<dim3(kL / 64, kP / 64, kB), 256, 0, stream>>>(Bbar, input_sequence, Bu);
    k_scanF<<<dim3(kB * kP), 256, 0, stream>>>(Bu, Lbar);
    k_gemm2F<<<dim3(kL / 64, kH / 64, kB), 256, 0, stream>>>(
        (const float2*)C, (const float2*)Bu, input_sequence, D, out);
  }
}

// Round 5
// 325.223 us; speedup vs baseline: 3.2455x; 1.2131x over previous
//
#include <hip/hip_runtime.h>
#include <math.h>

// S5 SSM forward — plain-bf16 MFMA GEMMs + proven fp32 inter-GEMM path (R5).
// BSZ=4, L=4096, H=1024, P=512.
// prep(A1=[Bbar_re;Bbar_im] bf16, A2=[2Cr|-2Ci] bf16, Lambda_bar)
//   -> transpose u fp32[b][h][l] -> uT bf16 [b][l][h]
//   -> GEMM1 (MFMA 1-term): Bu fp32 [b][m][l], m = p (re) / 512+p (im)
//   -> scan (fp32 planar, in-place)   [R3 replay-proven]
//   -> transpose xs fp32 -> xsT bf16 [b][l][m]   [R3 replay-proven]
//   -> GEMM2 (MFMA 1-term) + D*u + exact GeLU -> out fp32 [b][h][l]

constexpr int kB = 4, kL = 4096, kH = 1024, kP = 512;
constexpr int kM = 1024, kK = 1024, kN = 4096;

typedef short bf16x8 __attribute__((ext_vector_type(8)));
typedef float f32x4 __attribute__((ext_vector_type(4)));

// ---- ws layout (bytes), MFMA path
constexpr size_t A1H_OFF = 0;                                    // 2 MiB
constexpr size_t A2H_OFF = A1H_OFF + (size_t)kM * kK * 2;        // 2 MiB
constexpr size_t LBAR_B  = A2H_OFF + (size_t)kM * kK * 2;        // 4 KiB
constexpr size_t BU_B    = (LBAR_B + 4096 + 255) & ~(size_t)255; // 64 MiB fp32
constexpr size_t TH_B    = BU_B + (size_t)kB * kM * kN * 4;      // 32 MiB bf16
constexpr size_t MID_BYTES = TH_B + (size_t)kB * kN * kK * 2;    // ~100 MiB

// ---- bf16 helpers
__device__ __forceinline__ unsigned short f2bf(float x) {
  unsigned int u = __float_as_uint(x);
  u += 0x7fffu + ((u >> 16) & 1u);
  return (unsigned short)(u >> 16);
}
__device__ __forceinline__ float bf2f(unsigned short h) {
  return __uint_as_float(((unsigned int)h) << 16);
}

__device__ __forceinline__ void gl2lds16(const void* g, void* l) {
  __builtin_amdgcn_global_load_lds(
      (const __attribute__((address_space(1))) void*)g,
      (__attribute__((address_space(3))) void*)l, 16, 0, 0);
}

// ---------------------------------------------------------------- prep1
__global__ __launch_bounds__(256) void k_prep1(
    const float* __restrict__ Lre, const float* __restrict__ Lim,
    const float* __restrict__ B, const float* __restrict__ log_step,
    unsigned char* __restrict__ ws) {
  int p = blockIdx.x;
  float lr = Lre[p], li = Lim[p];
  float step = expf(log_step[p]);
  float er = expf(lr * step);
  float sb, cb;
  sincosf(li * step, &sb, &cb);
  float lbr = er * cb, lbi = er * sb;
  float nr = lbr - 1.0f, ni = lbi;
  float inv = 1.0f / (lr * lr + li * li);
  float sr = (nr * lr + ni * li) * inv;
  float si = (ni * lr - nr * li) * inv;

  if (threadIdx.x == 0) ((float2*)(ws + LBAR_B))[p] = make_float2(lbr, lbi);

  unsigned short* a1h = (unsigned short*)(ws + A1H_OFF);
  const float* Brow = B + (size_t)p * kH * 2;
  for (int h = threadIdx.x; h < kH; h += 256) {
    float br = Brow[2 * h], bi = Brow[2 * h + 1];
    a1h[(size_t)p * kK + h] = f2bf(sr * br - si * bi);
    a1h[(size_t)(kP + p) * kK + h] = f2bf(sr * bi + si * br);
  }
}

// ---------------------------------------------------------------- prep2
// A2[h][k] = 2*Cr[h][k] (k<512) | -2*Ci[h][k-512]
__global__ __launch_bounds__(256) void k_prep2(
    const float* __restrict__ C, unsigned char* __restrict__ ws) {
  int h = blockIdx.x;
  unsigned short* a2h = (unsigned short*)(ws + A2H_OFF);
  for (int k = threadIdx.x; k < kK; k += 256) {
    float v = (k < kP) ? 2.f * C[((size_t)h * kP + k) * 2]
                       : -2.f * C[((size_t)h * kP + (k - kP)) * 2 + 1];
    a2h[(size_t)h * kK + k] = f2bf(v);
  }
}

// ---------------------------------------------------------------- transpose (fp32 -> bf16T)
// in: fp32 [b][1024][4096] -> out: bf16 [b][4096][1024]   [R3 replay-proven]
__global__ __launch_bounds__(256) void k_transpose(
    const float* __restrict__ in, unsigned short* __restrict__ oh) {
  __shared__ float t[64][65];
  int b = blockIdx.z;
  int r0 = blockIdx.y * 64;
  int c0 = blockIdx.x * 64;
  int tid = threadIdx.x;
  const float* src = in + ((size_t)b * 1024 + r0) * 4096 + c0;
  int cc = (tid & 15) * 4, rr = tid >> 4;
#pragma unroll
  for (int i = 0; i < 4; i++) {
    float4 v = *(const float4*)(src + (size_t)(rr + i * 16) * 4096 + cc);
    t[rr + i * 16][cc + 0] = v.x;
    t[rr + i * 16][cc + 1] = v.y;
    t[rr + i * 16][cc + 2] = v.z;
    t[rr + i * 16][cc + 3] = v.w;
  }
  __syncthreads();
  int oc = tid >> 2;
  int og = (tid & 3) * 2;
#pragma unroll
  for (int i = 0; i < 2; i++) {
    int g = og + i;
    unsigned short hv[8];
#pragma unroll
    for (int j = 0; j < 8; j++) hv[j] = f2bf(t[g * 8 + j][oc]);
    size_t ob = ((size_t)b * 4096 + c0 + oc) * 1024 + r0 + g * 8;
    *(uint4*)(oh + ob) = *(uint4*)hv;
  }
}

// ---------------------------------------------------------------- GEMM (1-term bf16)
// out[b][m][n] = sum_k A[m][k] * Bm[b][n][k], fp32 out.
// EPI: y = acc + D[m]*u[b][m][n]; gelu(y)
template <bool EPI>
__global__ __launch_bounds__(256) void k_gemm(
    const unsigned short* __restrict__ Ah, const unsigned short* __restrict__ Bh,
    float* __restrict__ out, const float* __restrict__ u,
    const float* __restrict__ D) {
  __shared__ unsigned short sAh[128 * 32], sBh[128 * 32];
  int b = blockIdx.z;
  int m0 = blockIdx.y * 128, n0 = blockIdx.x * 128;
  int tid = threadIdx.x, lane = tid & 63, w = tid >> 6;
  int wm = (w & 1) * 64, wn = (w >> 1) * 64;
  int quad = lane >> 4, r = lane & 15;

  f32x4 acc[4][4] = {};

  const size_t bstride = (size_t)b * kN * kK;

  for (int k0 = 0; k0 < kK; k0 += 32) {
#pragma unroll
    for (int pass = 0; pass < 2; pass++) {
      int c = tid + pass * 256;             // chunk 0..511
      int row = c >> 2;
      int kg = (c & 3) ^ (row & 3);         // bank swizzle
      size_t ga = (size_t)(m0 + row) * kK + k0 + kg * 8;
      size_t gb = bstride + (size_t)(n0 + row) * kK + k0 + kg * 8;
      gl2lds16(Ah + ga, sAh + c * 8);
      gl2lds16(Bh + gb, sBh + c * 8);
    }
    __syncthreads();

    bf16x8 ah[4];
#pragma unroll
    for (int mi = 0; mi < 4; mi++) {
      int R = wm + mi * 16 + r;
      int ch = R * 4 + (quad ^ (R & 3));
      ah[mi] = ((const bf16x8*)sAh)[ch];
    }
#pragma unroll
    for (int ni = 0; ni < 4; ni++) {
      int R = wn + ni * 16 + r;
      int ch = R * 4 + (quad ^ (R & 3));
      bf16x8 bh = ((const bf16x8*)sBh)[ch];
#pragma unroll
      for (int mi = 0; mi < 4; mi++)
        acc[mi][ni] = __builtin_amdgcn_mfma_f32_16x16x32_bf16(ah[mi], bh, acc[mi][ni], 0, 0, 0);
    }
    __syncthreads();
  }

  // C/D layout: col = lane&15, row = quad*4 + reg
#pragma unroll
  for (int mi = 0; mi < 4; mi++) {
#pragma unroll
    for (int reg = 0; reg < 4; reg++) {
      int row = m0 + wm + mi * 16 + quad * 4 + reg;
      float dv = EPI ? D[row] : 0.f;
#pragma unroll
      for (int ni = 0; ni < 4; ni++) {
        int col = n0 + wn + ni * 16 + r;
        size_t o = ((size_t)b * kM + row) * (size_t)kN + col;
        float v = acc[mi][ni][reg];
        if (EPI) {
          float y = v + dv * u[o];
          v = 0.5f * y * (1.f + erff(y * 0.70710678118654752f));
        }
        out[o] = v;
      }
    }
  }
}

// ---------------------------------------------------------------- scan (fp32 planar, in-place)
// [R3 replay-proven]
__global__ __launch_bounds__(256) void k_scan(float* __restrict__ bu,
                                              const float2* __restrict__ lbar) {
  int p = blockIdx.x & (kP - 1);
  int b = blockIdx.x >> 9;
  int tid = threadIdx.x, lane = tid & 63, w = tid >> 6;
  float2 lam = lbar[p];
  float* sre = bu + ((size_t)b * kM + p) * (size_t)kN;
  float* sim = sre + (size_t)kP * kN;

  float vr[16], vi[16];
  {
    const float4* pr = (const float4*)(sre + tid * 16);
    const float4* pi = (const float4*)(sim + tid * 16);
#pragma unroll
    for (int i = 0; i < 4; i++) {
      float4 a = pr[i], c = pi[i];
      vr[4 * i] = a.x; vr[4 * i + 1] = a.y; vr[4 * i + 2] = a.z; vr[4 * i + 3] = a.w;
      vi[4 * i] = c.x; vi[4 * i + 1] = c.y; vi[4 * i + 2] = c.z; vi[4 * i + 3] = c.w;
    }
  }

  float xr = 0.f, xi = 0.f;
#pragma unroll
  for (int i = 0; i < 16; i++) {
    float nr2 = fmaf(lam.x, xr, fmaf(-lam.y, xi, vr[i]));
    float ni2 = fmaf(lam.x, xi, fmaf(lam.y, xr, vi[i]));
    xr = nr2; xi = ni2;
  }

  float Ar = lam.x, Ai = lam.y;
#pragma unroll
  for (int s = 0; s < 4; s++) {
    float tr = Ar * Ar - Ai * Ai, ti = 2.f * Ar * Ai;
    Ar = tr; Ai = ti;
  }
  float br = xr, bi = xi;

  for (int off = 1; off < 64; off <<= 1) {
    float pAr = __shfl_up(Ar, off), pAi = __shfl_up(Ai, off);
    float pbr = __shfl_up(br, off), pbi = __shfl_up(bi, off);
    if (lane >= off) {
      float nAr = Ar * pAr - Ai * pAi;
      float nAi = Ar * pAi + Ai * pAr;
      float nbr = Ar * pbr - Ai * pbi + br;
      float nbi = Ar * pbi + Ai * pbr + bi;
      Ar = nAr; Ai = nAi; br = nbr; bi = nbi;
    }
  }

  __shared__ float4 wtot[4];
  if (lane == 63) wtot[w] = make_float4(Ar, Ai, br, bi);
  __syncthreads();

  float eAr = __shfl_up(Ar, 1), eAi = __shfl_up(Ai, 1);
  float ebr = __shfl_up(br, 1), ebi = __shfl_up(bi, 1);
  if (lane == 0) { eAr = 1.f; eAi = 0.f; ebr = 0.f; ebi = 0.f; }

  float pAr = 1.f, pAi = 0.f, pbr = 0.f, pbi = 0.f;
  for (int j = 0; j < w; j++) {
    float4 t = wtot[j];
    float nAr = t.x * pAr - t.y * pAi;
    float nAi = t.x * pAi + t.y * pAr;
    float nbr = t.x * pbr - t.y * pbi + t.z;
    float nbi = t.x * pbi + t.y * pbr + t.w;
    pAr = nAr; pAi = nAi; pbr = nbr; pbi = nbi;
  }

  float initr = eAr * pbr - eAi * pbi + ebr;
  float initi = eAr * pbi + eAi * pbr + ebi;

  xr = initr; xi = initi;
  float4* qr = (float4*)(sre + tid * 16);
  float4* qi = (float4*)(sim + tid * 16);
#pragma unroll
  for (int i = 0; i < 4; i++) {
    float rr[4], ii[4];
#pragma unroll
    for (int j = 0; j < 4; j++) {
      float nr2 = fmaf(lam.x, xr, fmaf(-lam.y, xi, vr[4 * i + j]));
      float ni2 = fmaf(lam.x, xi, fmaf(lam.y, xr, vi[4 * i + j]));
      xr = nr2; xi = ni2; rr[j] = nr2; ii[j] = ni2;
    }
    qr[i] = make_float4(rr[0], rr[1], rr[2], rr[3]);
    qi[i] = make_float4(ii[0], ii[1], ii[2], ii[3]);
  }
}

// ================================================================ fp32 fallback
constexpr size_t OBBAR = 0;
constexpr size_t OLBAR = (size_t)kP * kH;
constexpr size_t OBU = OLBAR + 1024;

__global__ __launch_bounds__(256) void k_precomputeF(
    const float* __restrict__ Lre, const float* __restrict__ Lim,
    const float* __restrict__ B, const float* __restrict__ log_step,
    float2* __restrict__ ws) {
  int p = blockIdx.x;
  float lr = Lre[p], li = Lim[p];
  float step = expf(log_step[p]);
  float er = expf(lr * step);
  float sb, cb;
  sincosf(li * step, &sb, &cb);
  float lbr = er * cb, lbi = er * sb;
  float nr = lbr - 1.0f, ni = lbi;
  float inv = 1.0f / (lr * lr + li * li);
  float sr = (nr * lr + ni * li) * inv;
  float si = (ni * lr - nr * li) * inv;
  if (threadIdx.x == 0) ws[OLBAR + p] = make_float2(lbr, lbi);
  float2* Bbar = ws + OBBAR;
  const float* Brow = B + (size_t)p * kH * 2;
  for (int h = threadIdx.x; h < kH; h += 256) {
    float br = Brow[2 * h], bi = Brow[2 * h + 1];
    Bbar[(size_t)p * kH + h] = make_float2(sr * br - si * bi, sr * bi + si * br);
  }
}

__global__ __launch_bounds__(256) void k_gemm1F(
    const float2* __restrict__ ws_bbar, const float* __restrict__ u,
    float2* __restrict__ Bu) {
  __shared__ float2 As[16][64];
  __shared__ float Bs[16][64];
  int b = blockIdx.z, m0 = blockIdx.y * 64, n0 = blockIdx.x * 64;
  int tid = threadIdx.x, tn = tid & 15, tm = tid >> 4;
  const float* uB = u + (size_t)b * kH * kL;
  float2 acc[4][4];
#pragma unroll
  for (int i = 0; i < 4; i++)
#pragma unroll
    for (int j = 0; j < 4; j++) acc[i][j] = make_float2(0.f, 0.f);
  int ar = tid >> 2, ac = (tid & 3) * 4, bk = tid >> 4, bc = (tid & 15) * 4;
  for (int k0 = 0; k0 < kH; k0 += 16) {
    const float4* src = (const float4*)(ws_bbar + (size_t)(m0 + ar) * kH + k0 + ac);
    float4 v01 = src[0], v23 = src[1];
    As[ac + 0][ar] = make_float2(v01.x, v01.y);
    As[ac + 1][ar] = make_float2(v01.z, v01.w);
    As[ac + 2][ar] = make_float2(v23.x, v23.y);
    As[ac + 3][ar] = make_float2(v23.z, v23.w);
    float4 v = *(const float4*)(uB + (size_t)(k0 + bk) * kL + n0 + bc);
    *(float4*)&Bs[bk][bc] = v;
    __syncthreads();
#pragma unroll
    for (int kk = 0; kk < 16; ++kk) {
      const float4* arow = (const float4*)&As[kk][0];
      float4 a01 = arow[tm * 2 + 0], a23 = arow[tm * 2 + 1];
      float2 a[4] = {make_float2(a01.x, a01.y), make_float2(a01.z, a01.w),
                     make_float2(a23.x, a23.y), make_float2(a23.z, a23.w)};
      float4 bv = ((const float4*)&Bs[kk][0])[tn];
      float bb[4] = {bv.x, bv.y, bv.z, bv.w};
#pragma unroll
      for (int mi = 0; mi < 4; mi++)
#pragma unroll
        for (int ni = 0; ni < 4; ni++) {
          acc[mi][ni].x = fmaf(a[mi].x, bb[ni], acc[mi][ni].x);
          acc[mi][ni].y = fmaf(a[mi].y, bb[ni], acc[mi][ni].y);
        }
    }
    __syncthreads();
  }
  float2* BuB = Bu + (size_t)b * kP * kL;
#pragma unroll
  for (int mi = 0; mi < 4; mi++) {
    int row = m0 + tm * 4 + mi;
    float2* dst = BuB + (size_t)row * kL + n0 + tn * 4;
    ((float4*)dst)[0] = make_float4(acc[mi][0].x, acc[mi][0].y, acc[mi][1].x, acc[mi][1].y);
    ((float4*)dst)[1] = make_float4(acc[mi][2].x, acc[mi][2].y, acc[mi][3].x, acc[mi][3].y);
  }
}

__global__ __launch_bounds__(256) void k_scanF(float2* __restrict__ Bu,
                                               const float2* __restrict__ Lbar) {
  int p = blockIdx.x & (kP - 1);
  int b = blockIdx.x >> 9;
  int tid = threadIdx.x, lane = tid & 63, w = tid >> 6;
  float2 lam = Lbar[p];
  float2* seq = Bu + ((size_t)b * kP + p) * kL;
  float2 v[16];
  const float4* src = (const float4*)(seq + tid * 16);
#pragma unroll
  for (int i = 0; i < 8; i++) {
    float4 t = src[i];
    v[2 * i] = make_float2(t.x, t.y);
    v[2 * i + 1] = make_float2(t.z, t.w);
  }
  float xr = 0.f, xi = 0.f;
#pragma unroll
  for (int i = 0; i < 16; i++) {
    float nr2 = fmaf(lam.x, xr, fmaf(-lam.y, xi, v[i].x));
    float ni2 = fmaf(lam.x, xi, fmaf(lam.y, xr, v[i].y));
    xr = nr2; xi = ni2;
  }
  float Ar = lam.x, Ai = lam.y;
#pragma unroll
  for (int s = 0; s < 4; s++) {
    float tr = Ar * Ar - Ai * Ai, ti = 2.f * Ar * Ai;
    Ar = tr; Ai = ti;
  }
  float br = xr, bi = xi;
  for (int off = 1; off < 64; off <<= 1) {
    float pAr = __shfl_up(Ar, off), pAi = __shfl_up(Ai, off);
    float pbr = __shfl_up(br, off), pbi = __shfl_up(bi, off);
    if (lane >= off) {
      float nAr = Ar * pAr - Ai * pAi, nAi = Ar * pAi + Ai * pAr;
      float nbr = Ar * pbr - Ai * pbi + br, nbi = Ar * pbi + Ai * pbr + bi;
      Ar = nAr; Ai = nAi; br = nbr; bi = nbi;
    }
  }
  __shared__ float4 wtot[4];
  if (lane == 63) wtot[w] = make_float4(Ar, Ai, br, bi);
  __syncthreads();
  float eAr = __shfl_up(Ar, 1), eAi = __shfl_up(Ai, 1);
  float ebr = __shfl_up(br, 1), ebi = __shfl_up(bi, 1);
  if (lane == 0) { eAr = 1.f; eAi = 0.f; ebr = 0.f; ebi = 0.f; }
  float pAr = 1.f, pAi = 0.f, pbr = 0.f, pbi = 0.f;
  for (int j = 0; j < w; j++) {
    float4 t = wtot[j];
    float nAr = t.x * pAr - t.y * pAi, nAi = t.x * pAi + t.y * pAr;
    float nbr = t.x * pbr - t.y * pbi + t.z, nbi = t.x * pbi + t.y * pbr + t.w;
    pAr = nAr; pAi = nAi; pbr = nbr; pbi = nbi;
  }
  float initr = eAr * pbr - eAi * pbi + ebr;
  float initi = eAr * pbi + eAi * pbr + ebi;
  xr = initr; xi = initi;
  float4* dst = (float4*)(seq + tid * 16);
#pragma unroll
  for (int i = 0; i < 8; i++) {
    float nr0 = fmaf(lam.x, xr, fmaf(-lam.y, xi, v[2 * i].x));
    float ni0 = fmaf(lam.x, xi, fmaf(lam.y, xr, v[2 * i].y));
    float nr1 = fmaf(lam.x, nr0, fmaf(-lam.y, ni0, v[2 * i + 1].x));
    float ni1 = fmaf(lam.x, ni0, fmaf(lam.y, nr0, v[2 * i + 1].y));
    dst[i] = make_float4(nr0, ni0, nr1, ni1);
    xr = nr1; xi = ni1;
  }
}

__global__ __launch_bounds__(256) void k_gemm2F(
    const float2* __restrict__ C, const float2* __restrict__ X,
    const float* __restrict__ u, const float* __restrict__ D,
    float* __restrict__ out) {
  __shared__ float2 As[16][64];
  __shared__ float2 Bs[16][64];
  int b = blockIdx.z, m0 = blockIdx.y * 64, n0 = blockIdx.x * 64;
  int tid = threadIdx.x, tn = tid & 15, tm = tid >> 4;
  const float2* Xb = X + (size_t)b * kP * kL;
  float acc[4][4];
#pragma unroll
  for (int i = 0; i < 4; i++)
#pragma unroll
    for (int j = 0; j < 4; j++) acc[i][j] = 0.f;
  int ar = tid >> 2, ac = (tid & 3) * 4, bk = tid >> 4, bc = (tid & 15) * 4;
  for (int k0 = 0; k0 < kP; k0 += 16) {
    const float4* src = (const float4*)(C + (size_t)(m0 + ar) * kP + k0 + ac);
    float4 v01 = src[0], v23 = src[1];
    As[ac + 0][ar] = make_float2(v01.x, v01.y);
    As[ac + 1][ar] = make_float2(v01.z, v01.w);
    As[ac + 2][ar] = make_float2(v23.x, v23.y);
    As[ac + 3][ar] = make_float2(v23.z, v23.w);
    const float4* srcb = (const float4*)(Xb + (size_t)(k0 + bk) * kL + n0 + bc);
    ((float4*)&Bs[bk][bc])[0] = srcb[0];
    ((float4*)&Bs[bk][bc])[1] = srcb[1];
    __syncthreads();
#pragma unroll
    for (int kk = 0; kk < 16; ++kk) {
      const float4* arow = (const float4*)&As[kk][0];
      float4 a01 = arow[tm * 2 + 0], a23 = arow[tm * 2 + 1];
      float2 a[4] = {make_float2(a01.x, a01.y), make_float2(a01.z, a01.w),
                     make_float2(a23.x, a23.y), make_float2(a23.z, a23.w)};
      const float4* brow = (const float4*)&Bs[kk][0];
      float4 b01 = brow[tn * 2 + 0], b23 = brow[tn * 2 + 1];
      float2 bb[4] = {make_float2(b01.x, b01.y), make_float2(b01.z, b01.w),
                      make_float2(b23.x, b23.y), make_float2(b23.z, b23.w)};
#pragma unroll
      for (int mi = 0; mi < 4; mi++)
#pragma unroll
        for (int ni = 0; ni < 4; ni++) {
          acc[mi][ni] = fmaf(a[mi].x, bb[ni].x, acc[mi][ni]);
          acc[mi][ni] = fmaf(-a[mi].y, bb[ni].y, acc[mi][ni]);
        }
    }
    __syncthreads();
  }
#pragma unroll
  for (int mi = 0; mi < 4; mi++) {
    int h = m0 + tm * 4 + mi;
    float d = D[h];
    const float* urow = u + ((size_t)b * kH + h) * kL + n0 + tn * 4;
    float4 uv = *(const float4*)urow;
    float uu[4] = {uv.x, uv.y, uv.z, uv.w};
    float res[4];
#pragma unroll
    for (int ni = 0; ni < 4; ni++) {
      float y = 2.f * acc[mi][ni] + d * uu[ni];
      res[ni] = 0.5f * y * (1.f + erff(y * 0.70710678118654752f));
    }
    float* orow = out + ((size_t)b * kH + h) * kL + n0 + tn * 4;
    *(float4*)orow = make_float4(res[0], res[1], res[2], res[3]);
  }
}

// ---------------------------------------------------------------- launch
extern "C" void kernel_launch(void* const* d_in, const int* in_sizes, int n_in,
                              void* d_out, int out_size, void* d_ws, size_t ws_size,
                              hipStream_t stream) {
  const float* input_sequence = (const float*)d_in[0];
  const float* Lambda_re = (const float*)d_in[2];
  const float* Lambda_im = (const float*)d_in[3];
  const float* B = (const float*)d_in[4];
  const float* C = (const float*)d_in[5];
  const float* D = (const float*)d_in[6];
  const float* log_step = (const float*)d_in[7];
  float* out = (float*)d_out;

  if (ws_size >= MID_BYTES) {
    unsigned char* ws = (unsigned char*)d_ws;
    unsigned short* a1h = (unsigned short*)(ws + A1H_OFF);
    unsigned short* a2h = (unsigned short*)(ws + A2H_OFF);
    float2* lbar = (float2*)(ws + LBAR_B);
    float* bu = (float*)(ws + BU_B);
    unsigned short* th = (unsigned short*)(ws + TH_B);

    k_prep1<<<dim3(kP), 256, 0, stream>>>(Lambda_re, Lambda_im, B, log_step, ws);
    k_prep2<<<dim3(kH), 256, 0, stream>>>(C, ws);

    dim3 tgrid(kL / 64, 1024 / 64, kB);
    dim3 ggrid(kN / 128, kM / 128, kB);

    k_transpose<<<tgrid, 256, 0, stream>>>(input_sequence, th);
    k_gemm<false><<<ggrid, 256, 0, stream>>>(a1h, th, bu, nullptr, nullptr);
    k_scan<<<dim3(kB * kP), 256, 0, stream>>>(bu, lbar);
    k_transpose<<<tgrid, 256, 0, stream>>>(bu, th);
    k_gemm<true><<<ggrid, 256, 0, stream>>>(a2h, th, out, input_sequence, D);
  } else {
    // fp32 fallback (round-1 path)
    float2* ws = (float2*)d_ws;
    float2* Bbar = ws + OBBAR;
    float2* Lbar = ws + OLBAR;
    float2* Bu = ws + OBU;
    k_precomputeF<<<dim3(kP), 256, 0, stream>>>(Lambda_re, Lambda_im, B, log_step, ws);
    k_gemm1F<<<dim3(kL / 64, kP / 64, kB), 256, 0, stream>>>(Bbar, input_sequence, Bu);
    k_scanF<<<dim3(kB * kP), 256, 0, stream>>>(Bu, Lbar);
    k_gemm2F<<<dim3(kL / 64, kH / 64, kB), 256, 0, stream>>>(
        (const float2*)C, (const float2*)Bu, input_sequence, D, out);
  }
}

// Round 6
// 314.220 us; speedup vs baseline: 3.3592x; 1.0350x over previous
//
#include <hip/hip_runtime.h>
#include <math.h>

// S5 SSM forward — plain-bf16 MFMA GEMMs with double-buffered staging (R6).
// BSZ=4, L=4096, H=1024, P=512.
// prep(A1=[Bbar_re;Bbar_im] bf16, A2=[2Cr|-2Ci] bf16, Lambda_bar)
//   -> transpose u fp32[b][h][l] -> uT bf16 [b][l][h]
//   -> GEMM1 (dbuf MFMA): Bu fp32 [b][m][l], m = p (re) / 512+p (im)
//   -> scan (fp32 planar, in-place)   [replay-proven]
//   -> transpose xs fp32 -> xsT bf16 [b][l][m]   [replay-proven]
//   -> GEMM2 (dbuf MFMA) + D*u + exact GeLU -> out fp32 [b][h][l]
//
// k_gemm K-loop uses explicit LDS double-buffer with raw s_barrier and
// fine-grained s_waitcnt vmcnt(4) so the prefetch for tile k+1 stays in
// flight across the barrier (m139-validated pattern).

constexpr int kB = 4, kL = 4096, kH = 1024, kP = 512;
constexpr int kM = 1024, kK = 1024, kN = 4096;

typedef short bf16x8 __attribute__((ext_vector_type(8)));
typedef float f32x4 __attribute__((ext_vector_type(4)));

// ---- ws layout (bytes), MFMA path
constexpr size_t A1H_OFF = 0;                                    // 2 MiB
constexpr size_t A2H_OFF = A1H_OFF + (size_t)kM * kK * 2;        // 2 MiB
constexpr size_t LBAR_B  = A2H_OFF + (size_t)kM * kK * 2;        // 4 KiB
constexpr size_t BU_B    = (LBAR_B + 4096 + 255) & ~(size_t)255; // 64 MiB fp32
constexpr size_t TH_B    = BU_B + (size_t)kB * kM * kN * 4;      // 32 MiB bf16
constexpr size_t MID_BYTES = TH_B + (size_t)kB * kN * kK * 2;    // ~100 MiB

// ---- bf16 helpers
__device__ __forceinline__ unsigned short f2bf(float x) {
  unsigned int u = __float_as_uint(x);
  u += 0x7fffu + ((u >> 16) & 1u);
  return (unsigned short)(u >> 16);
}
__device__ __forceinline__ float bf2f(unsigned short h) {
  return __uint_as_float(((unsigned int)h) << 16);
}

__device__ __forceinline__ void gl2lds16(const void* g, void* l) {
  __builtin_amdgcn_global_load_lds(
      (const __attribute__((address_space(1))) void*)g,
      (__attribute__((address_space(3))) void*)l, 16, 0, 0);
}

// s_waitcnt with vmcnt=N, lgkmcnt/expcnt = don't-care (gfx9 encoding:
// vmcnt[3:0]|[15:14], lgkmcnt[11:8], expcnt[6:4])
template <int N>
__device__ __forceinline__ void wait_vm() {
  __builtin_amdgcn_s_waitcnt((N & 15) | ((N >> 4) << 14) | (15 << 8) | (7 << 4));
}

// ---------------------------------------------------------------- prep1
__global__ __launch_bounds__(256) void k_prep1(
    const float* __restrict__ Lre, const float* __restrict__ Lim,
    const float* __restrict__ B, const float* __restrict__ log_step,
    unsigned char* __restrict__ ws) {
  int p = blockIdx.x;
  float lr = Lre[p], li = Lim[p];
  float step = expf(log_step[p]);
  float er = expf(lr * step);
  float sb, cb;
  sincosf(li * step, &sb, &cb);
  float lbr = er * cb, lbi = er * sb;
  float nr = lbr - 1.0f, ni = lbi;
  float inv = 1.0f / (lr * lr + li * li);
  float sr = (nr * lr + ni * li) * inv;
  float si = (ni * lr - nr * li) * inv;

  if (threadIdx.x == 0) ((float2*)(ws + LBAR_B))[p] = make_float2(lbr, lbi);

  unsigned short* a1h = (unsigned short*)(ws + A1H_OFF);
  const float* Brow = B + (size_t)p * kH * 2;
  for (int h = threadIdx.x; h < kH; h += 256) {
    float br = Brow[2 * h], bi = Brow[2 * h + 1];
    a1h[(size_t)p * kK + h] = f2bf(sr * br - si * bi);
    a1h[(size_t)(kP + p) * kK + h] = f2bf(sr * bi + si * br);
  }
}

// ---------------------------------------------------------------- prep2
// A2[h][k] = 2*Cr[h][k] (k<512) | -2*Ci[h][k-512]
__global__ __launch_bounds__(256) void k_prep2(
    const float* __restrict__ C, unsigned char* __restrict__ ws) {
  int h = blockIdx.x;
  unsigned short* a2h = (unsigned short*)(ws + A2H_OFF);
  for (int k = threadIdx.x; k < kK; k += 256) {
    float v = (k < kP) ? 2.f * C[((size_t)h * kP + k) * 2]
                       : -2.f * C[((size_t)h * kP + (k - kP)) * 2 + 1];
    a2h[(size_t)h * kK + k] = f2bf(v);
  }
}

// ---------------------------------------------------------------- transpose (fp32 -> bf16T)
// in: fp32 [b][1024][4096] -> out: bf16 [b][4096][1024]   [replay-proven]
__global__ __launch_bounds__(256) void k_transpose(
    const float* __restrict__ in, unsigned short* __restrict__ oh) {
  __shared__ float t[64][65];
  int b = blockIdx.z;
  int r0 = blockIdx.y * 64;
  int c0 = blockIdx.x * 64;
  int tid = threadIdx.x;
  const float* src = in + ((size_t)b * 1024 + r0) * 4096 + c0;
  int cc = (tid & 15) * 4, rr = tid >> 4;
#pragma unroll
  for (int i = 0; i < 4; i++) {
    float4 v = *(const float4*)(src + (size_t)(rr + i * 16) * 4096 + cc);
    t[rr + i * 16][cc + 0] = v.x;
    t[rr + i * 16][cc + 1] = v.y;
    t[rr + i * 16][cc + 2] = v.z;
    t[rr + i * 16][cc + 3] = v.w;
  }
  __syncthreads();
  int oc = tid >> 2;
  int og = (tid & 3) * 2;
#pragma unroll
  for (int i = 0; i < 2; i++) {
    int g = og + i;
    unsigned short hv[8];
#pragma unroll
    for (int j = 0; j < 8; j++) hv[j] = f2bf(t[g * 8 + j][oc]);
    size_t ob = ((size_t)b * 4096 + c0 + oc) * 1024 + r0 + g * 8;
    *(uint4*)(oh + ob) = *(uint4*)hv;
  }
}

// ---------------------------------------------------------------- GEMM (1-term bf16, dbuf)
// out[b][m][n] = sum_k A[m][k] * Bm[b][n][k], fp32 out.
// EPI: y = acc + D[m]*u[b][m][n]; gelu(y)
template <bool EPI>
__global__ __launch_bounds__(256) void k_gemm(
    const unsigned short* __restrict__ Ah, const unsigned short* __restrict__ Bh,
    float* __restrict__ out, const float* __restrict__ u,
    const float* __restrict__ D) {
  __shared__ unsigned short sAh[2][128 * 32], sBh[2][128 * 32];
  int b = blockIdx.z;
  int m0 = blockIdx.y * 128, n0 = blockIdx.x * 128;
  int tid = threadIdx.x, lane = tid & 63, w = tid >> 6;
  int wm = (w & 1) * 64, wn = (w >> 1) * 64;
  int quad = lane >> 4, r = lane & 15;

  f32x4 acc[4][4] = {};
  const size_t bstride = (size_t)b * kN * kK;

  // staging addresses: 2 chunks per thread per array, 4 loads total per stage
  int c0i = tid, c1i = tid + 256;
  int row0 = c0i >> 2, kg0 = (c0i & 3) ^ (row0 & 3);   // bank swizzle
  int row1 = c1i >> 2, kg1 = (c1i & 3) ^ (row1 & 3);
  const unsigned short* gA0 = Ah + (size_t)(m0 + row0) * kK + kg0 * 8;
  const unsigned short* gA1 = Ah + (size_t)(m0 + row1) * kK + kg1 * 8;
  const unsigned short* gB0 = Bh + bstride + (size_t)(n0 + row0) * kK + kg0 * 8;
  const unsigned short* gB1 = Bh + bstride + (size_t)(n0 + row1) * kK + kg1 * 8;

#define STAGE(K0, BUF)                                    \
  do {                                                    \
    gl2lds16(gA0 + (K0), &sAh[(BUF)][c0i * 8]);           \
    gl2lds16(gA1 + (K0), &sAh[(BUF)][c1i * 8]);           \
    gl2lds16(gB0 + (K0), &sBh[(BUF)][c0i * 8]);           \
    gl2lds16(gB1 + (K0), &sBh[(BUF)][c1i * 8]);           \
  } while (0)

  STAGE(0, 0);

  for (int k0 = 0; k0 < kK; k0 += 32) {
    int buf = (k0 >> 5) & 1;
    int nk = k0 + 32;
    if (nk < kK) {
      STAGE(nk, buf ^ 1);
      wait_vm<4>();   // the 4 just-issued prefetch loads stay in flight
    } else {
      wait_vm<0>();
    }
    __builtin_amdgcn_s_barrier();

    bf16x8 ah[4];
#pragma unroll
    for (int mi = 0; mi < 4; mi++) {
      int R = wm + mi * 16 + r;
      int ch = R * 4 + (quad ^ (R & 3));
      ah[mi] = ((const bf16x8*)sAh[buf])[ch];
    }
#pragma unroll
    for (int ni = 0; ni < 4; ni++) {
      int R = wn + ni * 16 + r;
      int ch = R * 4 + (quad ^ (R & 3));
      bf16x8 bh = ((const bf16x8*)sBh[buf])[ch];
#pragma unroll
      for (int mi = 0; mi < 4; mi++)
        acc[mi][ni] = __builtin_amdgcn_mfma_f32_16x16x32_bf16(ah[mi], bh, acc[mi][ni], 0, 0, 0);
    }
    __builtin_amdgcn_s_barrier();  // all reads of buf done before it's restaged
  }
#undef STAGE

  // C/D layout: col = lane&15, row = quad*4 + reg
#pragma unroll
  for (int mi = 0; mi < 4; mi++) {
#pragma unroll
    for (int reg = 0; reg < 4; reg++) {
      int row = m0 + wm + mi * 16 + quad * 4 + reg;
      float dv = EPI ? D[row] : 0.f;
#pragma unroll
      for (int ni = 0; ni < 4; ni++) {
        int col = n0 + wn + ni * 16 + r;
        size_t o = ((size_t)b * kM + row) * (size_t)kN + col;
        float v = acc[mi][ni][reg];
        if (EPI) {
          float y = v + dv * u[o];
          v = 0.5f * y * (1.f + erff(y * 0.70710678118654752f));
        }
        out[o] = v;
      }
    }
  }
}

// ---------------------------------------------------------------- scan (fp32 planar, in-place)
// [replay-proven]
__global__ __launch_bounds__(256) void k_scan(float* __restrict__ bu,
                                              const float2* __restrict__ lbar) {
  int p = blockIdx.x & (kP - 1);
  int b = blockIdx.x >> 9;
  int tid = threadIdx.x, lane = tid & 63, w = tid >> 6;
  float2 lam = lbar[p];
  float* sre = bu + ((size_t)b * kM + p) * (size_t)kN;
  float* sim = sre + (size_t)kP * kN;

  float vr[16], vi[16];
  {
    const float4* pr = (const float4*)(sre + tid * 16);
    const float4* pi = (const float4*)(sim + tid * 16);
#pragma unroll
    for (int i = 0; i < 4; i++) {
      float4 a = pr[i], c = pi[i];
      vr[4 * i] = a.x; vr[4 * i + 1] = a.y; vr[4 * i + 2] = a.z; vr[4 * i + 3] = a.w;
      vi[4 * i] = c.x; vi[4 * i + 1] = c.y; vi[4 * i + 2] = c.z; vi[4 * i + 3] = c.w;
    }
  }

  float xr = 0.f, xi = 0.f;
#pragma unroll
  for (int i = 0; i < 16; i++) {
    float nr2 = fmaf(lam.x, xr, fmaf(-lam.y, xi, vr[i]));
    float ni2 = fmaf(lam.x, xi, fmaf(lam.y, xr, vi[i]));
    xr = nr2; xi = ni2;
  }

  float Ar = lam.x, Ai = lam.y;
#pragma unroll
  for (int s = 0; s < 4; s++) {
    float tr = Ar * Ar - Ai * Ai, ti = 2.f * Ar * Ai;
    Ar = tr; Ai = ti;
  }
  float br = xr, bi = xi;

  for (int off = 1; off < 64; off <<= 1) {
    float pAr = __shfl_up(Ar, off), pAi = __shfl_up(Ai, off);
    float pbr = __shfl_up(br, off), pbi = __shfl_up(bi, off);
    if (lane >= off) {
      float nAr = Ar * pAr - Ai * pAi;
      float nAi = Ar * pAi + Ai * pAr;
      float nbr = Ar * pbr - Ai * pbi + br;
      float nbi = Ar * pbi + Ai * pbr + bi;
      Ar = nAr; Ai = nAi; br = nbr; bi = nbi;
    }
  }

  __shared__ float4 wtot[4];
  if (lane == 63) wtot[w] = make_float4(Ar, Ai, br, bi);
  __syncthreads();

  float eAr = __shfl_up(Ar, 1), eAi = __shfl_up(Ai, 1);
  float ebr = __shfl_up(br, 1), ebi = __shfl_up(bi, 1);
  if (lane == 0) { eAr = 1.f; eAi = 0.f; ebr = 0.f; ebi = 0.f; }

  float pAr = 1.f, pAi = 0.f, pbr = 0.f, pbi = 0.f;
  for (int j = 0; j < w; j++) {
    float4 t = wtot[j];
    float nAr = t.x * pAr - t.y * pAi;
    float nAi = t.x * pAi + t.y * pAr;
    float nbr = t.x * pbr - t.y * pbi + t.z;
    float nbi = t.x * pbi + t.y * pbr + t.w;
    pAr = nAr; pAi = nAi; pbr = nbr; pbi = nbi;
  }

  float initr = eAr * pbr - eAi * pbi + ebr;
  float initi = eAr * pbi + eAi * pbr + ebi;

  xr = initr; xi = initi;
  float4* qr = (float4*)(sre + tid * 16);
  float4* qi = (float4*)(sim + tid * 16);
#pragma unroll
  for (int i = 0; i < 4; i++) {
    float rr[4], ii[4];
#pragma unroll
    for (int j = 0; j < 4; j++) {
      float nr2 = fmaf(lam.x, xr, fmaf(-lam.y, xi, vr[4 * i + j]));
      float ni2 = fmaf(lam.x, xi, fmaf(lam.y, xr, vi[4 * i + j]));
      xr = nr2; xi = ni2; rr[j] = nr2; ii[j] = ni2;
    }
    qr[i] = make_float4(rr[0], rr[1], rr[2], rr[3]);
    qi[i] = make_float4(ii[0], ii[1], ii[2], ii[3]);
  }
}

// ================================================================ fp32 fallback
constexpr size_t OBBAR = 0;
constexpr size_t OLBAR = (size_t)kP * kH;
constexpr size_t OBU = OLBAR + 1024;

__global__ __launch_bounds__(256) void k_precomputeF(
    const float* __restrict__ Lre, const float* __restrict__ Lim,
    const float* __restrict__ B, const float* __restrict__ log_step,
    float2* __restrict__ ws) {
  int p = blockIdx.x;
  float lr = Lre[p], li = Lim[p];
  float step = expf(log_step[p]);
  float er = expf(lr * step);
  float sb, cb;
  sincosf(li * step, &sb, &cb);
  float lbr = er * cb, lbi = er * sb;
  float nr = lbr - 1.0f, ni = lbi;
  float inv = 1.0f / (lr * lr + li * li);
  float sr = (nr * lr + ni * li) * inv;
  float si = (ni * lr - nr * li) * inv;
  if (threadIdx.x == 0) ws[OLBAR + p] = make_float2(lbr, lbi);
  float2* Bbar = ws + OBBAR;
  const float* Brow = B + (size_t)p * kH * 2;
  for (int h = threadIdx.x; h < kH; h += 256) {
    float br = Brow[2 * h], bi = Brow[2 * h + 1];
    Bbar[(size_t)p * kH + h] = make_float2(sr * br - si * bi, sr * bi + si * br);
  }
}

__global__ __launch_bounds__(256) void k_gemm1F(
    const float2* __restrict__ ws_bbar, const float* __restrict__ u,
    float2* __restrict__ Bu) {
  __shared__ float2 As[16][64];
  __shared__ float Bs[16][64];
  int b = blockIdx.z, m0 = blockIdx.y * 64, n0 = blockIdx.x * 64;
  int tid = threadIdx.x, tn = tid & 15, tm = tid >> 4;
  const float* uB = u + (size_t)b * kH * kL;
  float2 acc[4][4];
#pragma unroll
  for (int i = 0; i < 4; i++)
#pragma unroll
    for (int j = 0; j < 4; j++) acc[i][j] = make_float2(0.f, 0.f);
  int ar = tid >> 2, ac = (tid & 3) * 4, bk = tid >> 4, bc = (tid & 15) * 4;
  for (int k0 = 0; k0 < kH; k0 += 16) {
    const float4* src = (const float4*)(ws_bbar + (size_t)(m0 + ar) * kH + k0 + ac);
    float4 v01 = src[0], v23 = src[1];
    As[ac + 0][ar] = make_float2(v01.x, v01.y);
    As[ac + 1][ar] = make_float2(v01.z, v01.w);
    As[ac + 2][ar] = make_float2(v23.x, v23.y);
    As[ac + 3][ar] = make_float2(v23.z, v23.w);
    float4 v = *(const float4*)(uB + (size_t)(k0 + bk) * kL + n0 + bc);
    *(float4*)&Bs[bk][bc] = v;
    __syncthreads();
#pragma unroll
    for (int kk = 0; kk < 16; ++kk) {
      const float4* arow = (const float4*)&As[kk][0];
      float4 a01 = arow[tm * 2 + 0], a23 = arow[tm * 2 + 1];
      float2 a[4] = {make_float2(a01.x, a01.y), make_float2(a01.z, a01.w),
                     make_float2(a23.x, a23.y), make_float2(a23.z, a23.w)};
      float4 bv = ((const float4*)&Bs[kk][0])[tn];
      float bb[4] = {bv.x, bv.y, bv.z, bv.w};
#pragma unroll
      for (int mi = 0; mi < 4; mi++)
#pragma unroll
        for (int ni = 0; ni < 4; ni++) {
          acc[mi][ni].x = fmaf(a[mi].x, bb[ni], acc[mi][ni].x);
          acc[mi][ni].y = fmaf(a[mi].y, bb[ni], acc[mi][ni].y);
        }
    }
    __syncthreads();
  }
  float2* BuB = Bu + (size_t)b * kP * kL;
#pragma unroll
  for (int mi = 0; mi < 4; mi++) {
    int row = m0 + tm * 4 + mi;
    float2* dst = BuB + (size_t)row * kL + n0 + tn * 4;
    ((float4*)dst)[0] = make_float4(acc[mi][0].x, acc[mi][0].y, acc[mi][1].x, acc[mi][1].y);
    ((float4*)dst)[1] = make_float4(acc[mi][2].x, acc[mi][2].y, acc[mi][3].x, acc[mi][3].y);
  }
}

__global__ __launch_bounds__(256) void k_scanF(float2* __restrict__ Bu,
                                               const float2* __restrict__ Lbar) {
  int p = blockIdx.x & (kP - 1);
  int b = blockIdx.x >> 9;
  int tid = threadIdx.x, lane = tid & 63, w = tid >> 6;
  float2 lam = Lbar[p];
  float2* seq = Bu + ((size_t)b * kP + p) * kL;
  float2 v[16];
  const float4* src = (const float4*)(seq + tid * 16);
#pragma unroll
  for (int i = 0; i < 8; i++) {
    float4 t = src[i];
    v[2 * i] = make_float2(t.x, t.y);
    v[2 * i + 1] = make_float2(t.z, t.w);
  }
  float xr = 0.f, xi = 0.f;
#pragma unroll
  for (int i = 0; i < 16; i++) {
    float nr2 = fmaf(lam.x, xr, fmaf(-lam.y, xi, v[i].x));
    float ni2 = fmaf(lam.x, xi, fmaf(lam.y, xr, v[i].y));
    xr = nr2; xi = ni2;
  }
  float Ar = lam.x, Ai = lam.y;
#pragma unroll
  for (int s = 0; s < 4; s++) {
    float tr = Ar * Ar - Ai * Ai, ti = 2.f * Ar * Ai;
    Ar = tr; Ai = ti;
  }
  float br = xr, bi = xi;
  for (int off = 1; off < 64; off <<= 1) {
    float pAr = __shfl_up(Ar, off), pAi = __shfl_up(Ai, off);
    float pbr = __shfl_up(br, off), pbi = __shfl_up(bi, off);
    if (lane >= off) {
      float nAr = Ar * pAr - Ai * pAi, nAi = Ar * pAi + Ai * pAr;
      float nbr = Ar * pbr - Ai * pbi + br, nbi = Ar * pbi + Ai * pbr + bi;
      Ar = nAr; Ai = nAi; br = nbr; bi = nbi;
    }
  }
  __shared__ float4 wtot[4];
  if (lane == 63) wtot[w] = make_float4(Ar, Ai, br, bi);
  __syncthreads();
  float eAr = __shfl_up(Ar, 1), eAi = __shfl_up(Ai, 1);
  float ebr = __shfl_up(br, 1), ebi = __shfl_up(bi, 1);
  if (lane == 0) { eAr = 1.f; eAi = 0.f; ebr = 0.f; ebi = 0.f; }
  float pAr = 1.f, pAi = 0.f, pbr = 0.f, pbi = 0.f;
  for (int j = 0; j < w; j++) {
    float4 t = wtot[j];
    float nAr = t.x * pAr - t.y * pAi, nAi = t.x * pAi + t.y * pAr;
    float nbr = t.x * pbr - t.y * pbi + t.z, nbi = t.x * pbi + t.y * pbr + t.w;
    pAr = nAr; pAi = nAi; pbr = nbr; pbi = nbi;
  }
  float initr = eAr * pbr - eAi * pbi + ebr;
  float initi = eAr * pbi + eAi * pbr + ebi;
  xr = initr; xi = initi;
  float4* dst = (float4*)(seq + tid * 16);
#pragma unroll
  for (int i = 0; i < 8; i++) {
    float nr0 = fmaf(lam.x, xr, fmaf(-lam.y, xi, v[2 * i].x));
    float ni0 = fmaf(lam.x, xi, fmaf(lam.y, xr, v[2 * i].y));
    float nr1 = fmaf(lam.x, nr0, fmaf(-lam.y, ni0, v[2 * i + 1].x));
    float ni1 = fmaf(lam.x, ni0, fmaf(lam.y, nr0, v[2 * i + 1].y));
    dst[i] = make_float4(nr0, ni0, nr1, ni1);
    xr = nr1; xi = ni1;
  }
}

__global__ __launch_bounds__(256) void k_gemm2F(
    const float2* __restrict__ C, const float2* __restrict__ X,
    const float* __restrict__ u, const float* __restrict__ D,
    float* __restrict__ out) {
  __shared__ float2 As[16][64];
  __shared__ float2 Bs[16][64];
  int b = blockIdx.z, m0 = blockIdx.y * 64, n0 = blockIdx.x * 64;
  int tid = threadIdx.x, tn = tid & 15, tm = tid >> 4;
  const float2* Xb = X + (size_t)b * kP * kL;
  float acc[4][4];
#pragma unroll
  for (int i = 0; i < 4; i++)
#pragma unroll
    for (int j = 0; j < 4; j++) acc[i][j] = 0.f;
  int ar = tid >> 2, ac = (tid & 3) * 4, bk = tid >> 4, bc = (tid & 15) * 4;
  for (int k0 = 0; k0 < kP; k0 += 16) {
    const float4* src = (const float4*)(C + (size_t)(m0 + ar) * kP + k0 + ac);
    float4 v01 = src[0], v23 = src[1];
    As[ac + 0][ar] = make_float2(v01.x, v01.y);
    As[ac + 1][ar] = make_float2(v01.z, v01.w);
    As[ac + 2][ar] = make_float2(v23.x, v23.y);
    As[ac + 3][ar] = make_float2(v23.z, v23.w);
    const float4* srcb = (const float4*)(Xb + (size_t)(k0 + bk) * kL + n0 + bc);
    ((float4*)&Bs[bk][bc])[0] = srcb[0];
    ((float4*)&Bs[bk][bc])[1] = srcb[1];
    __syncthreads();
#pragma unroll
    for (int kk = 0; kk < 16; ++kk) {
      const float4* arow = (const float4*)&As[kk][0];
      float4 a01 = arow[tm * 2 + 0], a23 = arow[tm * 2 + 1];
      float2 a[4] = {make_float2(a01.x, a01.y), make_float2(a01.z, a01.w),
                     make_float2(a23.x, a23.y), make_float2(a23.z, a23.w)};
      const float4* brow = (const float4*)&Bs[kk][0];
      float4 b01 = brow[tn * 2 + 0], b23 = brow[tn * 2 + 1];
      float2 bb[4] = {make_float2(b01.x, b01.y), make_float2(b01.z, b01.w),
                      make_float2(b23.x, b23.y), make_float2(b23.z, b23.w)};
#pragma unroll
      for (int mi = 0; mi < 4; mi++)
#pragma unroll
        for (int ni = 0; ni < 4; ni++) {
          acc[mi][ni] = fmaf(a[mi].x, bb[ni].x, acc[mi][ni]);
          acc[mi][ni] = fmaf(-a[mi].y, bb[ni].y, acc[mi][ni]);
        }
    }
    __syncthreads();
  }
#pragma unroll
  for (int mi = 0; mi < 4; mi++) {
    int h = m0 + tm * 4 + mi;
    float d = D[h];
    const float* urow = u + ((size_t)b * kH + h) * kL + n0 + tn * 4;
    float4 uv = *(const float4*)urow;
    float uu[4] = {uv.x, uv.y, uv.z, uv.w};
    float res[4];
#pragma unroll
    for (int ni = 0; ni < 4; ni++) {
      float y = 2.f * acc[mi][ni] + d * uu[ni];
      res[ni] = 0.5f * y * (1.f + erff(y * 0.70710678118654752f));
    }
    float* orow = out + ((size_t)b * kH + h) * kL + n0 + tn * 4;
    *(float4*)orow = make_float4(res[0], res[1], res[2], res[3]);
  }
}

// ---------------------------------------------------------------- launch
extern "C" void kernel_launch(void* const* d_in, const int* in_sizes, int n_in,
                              void* d_out, int out_size, void* d_ws, size_t ws_size,
                              hipStream_t stream) {
  const float* input_sequence = (const float*)d_in[0];
  const float* Lambda_re = (const float*)d_in[2];
  const float* Lambda_im = (const float*)d_in[3];
  const float* B = (const float*)d_in[4];
  const float* C = (const float*)d_in[5];
  const float* D = (const float*)d_in[6];
  const float* log_step = (const float*)d_in[7];
  float* out = (float*)d_out;

  if (ws_size >= MID_BYTES) {
    unsigned char* ws = (unsigned char*)d_ws;
    unsigned short* a1h = (unsigned short*)(ws + A1H_OFF);
    unsigned short* a2h = (unsigned short*)(ws + A2H_OFF);
    float2* lbar = (float2*)(ws + LBAR_B);
    float* bu = (float*)(ws + BU_B);
    unsigned short* th = (unsigned short*)(ws + TH_B);

    k_prep1<<<dim3(kP), 256, 0, stream>>>(Lambda_re, Lambda_im, B, log_step, ws);
    k_prep2<<<dim3(kH), 256, 0, stream>>>(C, ws);

    dim3 tgrid(kL / 64, 1024 / 64, kB);
    dim3 ggrid(kN / 128, kM / 128, kB);

    k_transpose<<<tgrid, 256, 0, stream>>>(input_sequence, th);
    k_gemm<false><<<ggrid, 256, 0, stream>>>(a1h, th, bu, nullptr, nullptr);
    k_scan<<<dim3(kB * kP), 256, 0, stream>>>(bu, lbar);
    k_transpose<<<tgrid, 256, 0, stream>>>(bu, th);
    k_gemm<true><<<ggrid, 256, 0, stream>>>(a2h, th, out, input_sequence, D);
  } else {
    // fp32 fallback (round-1 path)
    float2* ws = (float2*)d_ws;
    float2* Bbar = ws + OBBAR;
    float2* Lbar = ws + OLBAR;
    float2* Bu = ws + OBU;
    k_precomputeF<<<dim3(kP), 256, 0, stream>>>(Lambda_re, Lambda_im, B, log_step, ws);
    k_gemm1F<<<dim3(kL / 64, kP / 64, kB), 256, 0, stream>>>(Bbar, input_sequence, Bu);
    k_scanF<<<dim3(kB * kP), 256, 0, stream>>>(Bu, Lbar);
    k_gemm2F<<<dim3(kL / 64, kH / 64, kB), 256, 0, stream>>>(
        (const float2*)C, (const float2*)Bu, input_sequence, D, out);
  }
}